// Round 15
// baseline (4702.962 us; speedup 1.0000x reference)
//
#include <hip/hip_runtime.h>
#include <cstdint>
#include <cstddef>

#define IN_F 4096
#define OUT_F 4096

typedef __attribute__((ext_vector_type(8))) short bf16x8;
typedef __attribute__((ext_vector_type(4))) float f32x4;
typedef __attribute__((ext_vector_type(16))) float f32x16;

__device__ __forceinline__ ushort f32_bf16_rne(float f) {
    uint32_t u = __builtin_bit_cast(uint32_t, f);
    uint32_t r = (u + 0x7FFFu + ((u >> 16) & 1u)) >> 16;
    return (ushort)r;
}

__device__ __forceinline__ float bf16_f32(ushort u) {
    return __builtin_bit_cast(float, (uint32_t)u << 16);
}

__device__ __forceinline__ void gload_lds16(const void* g, void* l) {
    __builtin_amdgcn_global_load_lds(
        (const __attribute__((address_space(1))) uint32_t*)g,
        (__attribute__((address_space(3))) uint32_t*)l,
        16, 0, 0);
}

// ---------- fused prologue (validated R14) ----------
__global__ void fused_reduce_cast(const float* __restrict__ W,
                                  float* __restrict__ part,
                                  const float* __restrict__ X,
                                  ushort* __restrict__ xh) {
    const int t = threadIdx.x;
    if (blockIdx.x < 4096) {
        __shared__ float sm[256];
        const int b = blockIdx.x;
        const float* p = W + (size_t)b * 4096;
        float s = 0.f;
#pragma unroll
        for (int j = 0; j < 16; ++j) s += fabsf(p[t + 256 * j]);
        sm[t] = s;
        __syncthreads();
        for (int w = 128; w > 0; w >>= 1) {
            if (t < w) sm[t] += sm[t + w];
            __syncthreads();
        }
        if (t == 0) part[b] = sm[0];
    } else {
        const int i = (blockIdx.x - 4096) * 256 + t;
        float4 v = ((const float4*)X)[i];
        ushort4 o;
        o.x = f32_bf16_rne(v.x); o.y = f32_bf16_rne(v.y);
        o.z = f32_bf16_rne(v.z); o.w = f32_bf16_rne(v.w);
        ((ushort4*)xh)[i] = o;
    }
}

__global__ void reduce_abs1(const float* __restrict__ W, float* __restrict__ part) {
    __shared__ float sm[256];
    const int b = blockIdx.x, t = threadIdx.x;
    const float* p = W + (size_t)b * 4096;
    float s = 0.f;
#pragma unroll
    for (int j = 0; j < 16; ++j) s += fabsf(p[t + 256 * j]);
    sm[t] = s;
    __syncthreads();
    for (int w = 128; w > 0; w >>= 1) {
        if (t < w) sm[t] += sm[t + w];
        __syncthreads();
    }
    if (t == 0) part[b] = sm[0];
}

__global__ void reduce_abs2(const float* __restrict__ part, float* __restrict__ scale) {
    __shared__ float sm[256];
    const int t = threadIdx.x;
    float s = 0.f;
#pragma unroll
    for (int j = 0; j < 16; ++j) s += part[t + 256 * j];
    sm[t] = s;
    __syncthreads();
    for (int w = 128; w > 0; w >>= 1) {
        if (t < w) sm[t] += sm[t + w];
        __syncthreads();
    }
    if (t == 0) {
        float m = sm[0] / 16777216.0f;
        *scale = fmaxf(m, 1e-8f);
    }
}

__global__ void quantize_w(const float* __restrict__ W, ushort* __restrict__ wq,
                           const float* __restrict__ scale_p) {
    const int i = blockIdx.x * 256 + threadIdx.x;
    const float s = *scale_p;
    float4 v = ((const float4*)W)[i];
    float q0 = fminf(fmaxf(rintf(v.x / s), -2.f), 2.f);
    float q1 = fminf(fmaxf(rintf(v.y / s), -2.f), 2.f);
    float q2 = fminf(fmaxf(rintf(v.z / s), -2.f), 2.f);
    float q3 = fminf(fmaxf(rintf(v.w / s), -2.f), 2.f);
    ushort4 o;
    o.x = f32_bf16_rne(q0); o.y = f32_bf16_rne(q1);
    o.z = f32_bf16_rne(q2); o.w = f32_bf16_rne(q3);
    ((ushort4*)wq)[i] = o;
}

__global__ void cast_x(const float* __restrict__ X, ushort* __restrict__ xh) {
    const int i = blockIdx.x * 256 + threadIdx.x;
    float4 v = ((const float4*)X)[i];
    ushort4 o;
    o.x = f32_bf16_rne(v.x); o.y = f32_bf16_rne(v.y);
    o.z = f32_bf16_rne(v.z); o.w = f32_bf16_rne(v.w);
    ((ushort4*)xh)[i] = o;
}

// ======= 256x256 GEMM: R12 schedule (best validated: 256us, 47%) ===========
#define BK 64
#define BUF_BYTES 65536

__global__ __launch_bounds__(512, 2) void qgemm256(
        const ushort* __restrict__ Ab, const ushort* __restrict__ Bq,
        float* __restrict__ C, const float* __restrict__ scale_p,
        int M, int N, int K) {
    extern __shared__ __align__(16) char smem[];

    const int t = threadIdx.x;
    const int lane = t & 63;
    const int w = t >> 6;
    const int wr = w >> 2;
    const int wc = w & 3;
    const int bh = wc >> 1;

    const int MT = M >> 8;
    const int NTiles = N >> 8;
    int mt, nt;
    if (MT == 32 && NTiles == 16 && gridDim.x == 512) {
        const int x = blockIdx.x & 7;
        const int j = blockIdx.x >> 3;
        const int jr = j & 31;
        const int r = j >> 5;
        mt = (x & 3) * 8 + (jr & 7);
        nt = r * 8 + (x >> 2) * 4 + (jr >> 3);
    } else {
        const int nwg = gridDim.x;
        int wg = blockIdx.x;
        if ((nwg & 7) == 0) wg = (wg & 7) * (nwg >> 3) + (wg >> 3);
        mt = wg % MT; nt = wg / MT;
    }
    const int m0 = mt << 8;
    const int n0 = nt << 8;

    const int NT = K / BK;

    int pre[2];
#pragma unroll
    for (int ks = 0; ks < 2; ++ks)
        pre[ks] = (lane & 15) * 128 +
                  (((ks * 64) + ((lane >> 4) * 16)) ^ ((lane & 7) << 4));

    const int rowA = t >> 3;
    const int colsw = ((t & 7) ^ ((t >> 3) & 7)) << 3;
    const ushort* gA0 = Ab + (size_t)(m0 + rowA) * K + colsw;
    const ushort* gA1 = Ab + (size_t)(m0 + 128 + rowA) * K + colsw;
    const ushort* gB0 = Bq + (size_t)(n0 + rowA) * K + colsw;
    const ushort* gB1 = Bq + (size_t)(n0 + 128 + rowA) * K + colsw;
    const size_t jrow = (size_t)64 * K;
    char* lb = smem + t * 16;

    auto stA0 = [&](uint32_t par) {
        gload_lds16(gA0,        lb + par);
        gload_lds16(gA0 + jrow, lb + par + 8192);
        gA0 += 64;
    };
    auto stA1 = [&](uint32_t par) {
        gload_lds16(gA1,        lb + par + 16384);
        gload_lds16(gA1 + jrow, lb + par + 24576);
        gA1 += 64;
    };
    auto stB0 = [&](uint32_t par) {
        gload_lds16(gB0,        lb + par + 32768);
        gload_lds16(gB0 + jrow, lb + par + 40960);
        gB0 += 64;
    };
    auto stB1 = [&](uint32_t par) {
        gload_lds16(gB1,        lb + par + 49152);
        gload_lds16(gB1 + jrow, lb + par + 57344);
        gB1 += 64;
    };

    const char* aBbase = smem + wr * 16384;
    const char* bBbase = smem + 32768 + bh * 16384 + (wc & 1) * 8192;

    f32x4 acc[8][4];
#pragma unroll
    for (int m = 0; m < 8; ++m)
#pragma unroll
        for (int n = 0; n < 4; ++n) acc[m][n] = (f32x4){0.f, 0.f, 0.f, 0.f};

    stB0(0); stB1(0); stA0(0); stA1(0);
    stA0(BUF_BYTES); stA1(BUF_BYTES);
    asm volatile("s_waitcnt vmcnt(4)");
    __builtin_amdgcn_s_barrier();

    for (int kt = 0; kt < NT; ++kt) {
        const uint32_t cur = (uint32_t)(kt & 1) * BUF_BYTES;
        const uint32_t nxt = cur ^ BUF_BYTES;
        const char* aB = aBbase + cur;
        const char* bB = bBbase + cur;

        bf16x8 a0[4][2], a1[4][2], b01[2][2], b23[2][2];

#pragma unroll
        for (int n = 0; n < 2; ++n)
#pragma unroll
            for (int ks = 0; ks < 2; ++ks)
                b01[n][ks] = *(const bf16x8*)(bB + n * 2048 + pre[ks]);
#pragma unroll
        for (int m = 0; m < 4; ++m)
#pragma unroll
            for (int ks = 0; ks < 2; ++ks)
                a0[m][ks] = *(const bf16x8*)(aB + m * 2048 + pre[ks]);
        if (kt + 1 < NT) stB0(nxt);
        __builtin_amdgcn_s_barrier();
        asm volatile("s_waitcnt lgkmcnt(0)");
        __builtin_amdgcn_s_setprio(1);
#pragma unroll
        for (int m = 0; m < 4; ++m)
#pragma unroll
            for (int n = 0; n < 2; ++n)
#pragma unroll
                for (int ks = 0; ks < 2; ++ks)
                    acc[m][n] = __builtin_amdgcn_mfma_f32_16x16x32_bf16(
                        a0[m][ks], b01[n][ks], acc[m][n], 0, 0, 0);
        __builtin_amdgcn_s_setprio(0);
        __builtin_amdgcn_s_barrier();

#pragma unroll
        for (int m = 0; m < 4; ++m)
#pragma unroll
            for (int ks = 0; ks < 2; ++ks)
                a1[m][ks] = *(const bf16x8*)(aB + (m + 4) * 2048 + pre[ks]);
        if (kt + 1 < NT) stB1(nxt);
        __builtin_amdgcn_s_barrier();
        asm volatile("s_waitcnt lgkmcnt(0)");
        __builtin_amdgcn_s_setprio(1);
#pragma unroll
        for (int m = 0; m < 4; ++m)
#pragma unroll
            for (int n = 0; n < 2; ++n)
#pragma unroll
                for (int ks = 0; ks < 2; ++ks)
                    acc[m + 4][n] = __builtin_amdgcn_mfma_f32_16x16x32_bf16(
                        a1[m][ks], b01[n][ks], acc[m + 4][n], 0, 0, 0);
        __builtin_amdgcn_s_setprio(0);
        __builtin_amdgcn_s_barrier();

#pragma unroll
        for (int n = 0; n < 2; ++n)
#pragma unroll
            for (int ks = 0; ks < 2; ++ks)
                b23[n][ks] = *(const bf16x8*)(bB + (n + 2) * 2048 + pre[ks]);
        if (kt + 2 < NT) stA0(cur);
        __builtin_amdgcn_s_barrier();
        asm volatile("s_waitcnt lgkmcnt(0)");
        __builtin_amdgcn_s_setprio(1);
#pragma unroll
        for (int m = 0; m < 4; ++m)
#pragma unroll
            for (int n = 0; n < 2; ++n)
#pragma unroll
                for (int ks = 0; ks < 2; ++ks)
                    acc[m][n + 2] = __builtin_amdgcn_mfma_f32_16x16x32_bf16(
                        a0[m][ks], b23[n][ks], acc[m][n + 2], 0, 0, 0);
        __builtin_amdgcn_s_setprio(0);
        __builtin_amdgcn_s_barrier();

        if (kt + 2 < NT) stA1(cur);
        if (kt < NT - 2) {
            asm volatile("s_waitcnt vmcnt(4)");
        } else {
            asm volatile("s_waitcnt vmcnt(0)");
        }
        __builtin_amdgcn_s_barrier();
        asm volatile("s_waitcnt lgkmcnt(0)");
        __builtin_amdgcn_s_setprio(1);
#pragma unroll
        for (int m = 0; m < 4; ++m)
#pragma unroll
            for (int n = 0; n < 2; ++n)
#pragma unroll
                for (int ks = 0; ks < 2; ++ks)
                    acc[m + 4][n + 2] = __builtin_amdgcn_mfma_f32_16x16x32_bf16(
                        a1[m][ks], b23[n][ks], acc[m + 4][n + 2], 0, 0, 0);
        __builtin_amdgcn_s_setprio(0);
        __builtin_amdgcn_s_barrier();
    }

    const float s = *scale_p;
#pragma unroll
    for (int m = 0; m < 8; ++m)
#pragma unroll
        for (int n = 0; n < 4; ++n) {
            const int col = n0 + wc * 64 + n * 16 + (lane & 15);
            const int rbase = m0 + wr * 128 + m * 16 + ((lane >> 4) << 2);
#pragma unroll
            for (int j = 0; j < 4; ++j)
                C[(size_t)(rbase + j) * N + col] = s * acc[m][n][j];
        }
}

// ============================================================================
// R15 DIAGNOSTIC: 32x32x16 MFMA layout probe (self-checking; d_out untouched).
// 4 variants, K=512, tiles (mt=0..7, nt=0), vs fp32 oracle (bf16 products are
// exact in fp32 -> oracle is layout-immune).  Fail mask encoded as spin-kernel
// duration (s_memrealtime, 100 MHz):
//   no spin row ........ ws too small, diag skipped
//   ~500 us ............ ALL PASS (incl V0 -> R9 bug was structural)
//   600+200*mask us .... bit v set = variant v FAILED
//     V0 = R9 layout (A,B: k = 8*(lane>>5)+j)
//     V1 = B k-group inverted      V2 = B j-halves swapped
//     V3 = A k-group inverted
//   e.g. 3600=all fail; 3200=V1 ok; 2800=V2 ok; 2000=V3 ok; 3400=V0 ok.
// ============================================================================
template <int V>
__global__ __launch_bounds__(512) void qgemm32diag(
        const ushort* __restrict__ Ab, const ushort* __restrict__ Bq,
        float* __restrict__ C2, const float* __restrict__ scale_p,
        int Kstride, int Kloop) {
    extern __shared__ __align__(16) char smem[];
    const int t = threadIdx.x;
    const int lane = t & 63;
    const int w = t >> 6;
    const int wr = w >> 2;
    const int wc = w & 3;
    const int bh = wc >> 1;
    const int m0 = blockIdx.x << 8;   // tile mt = blockIdx.x, nt = 0
    const int NT = Kloop / 64;

    int gAg = (lane >> 5), gBg = (lane >> 5);
    if (V == 3) gAg ^= 1;
    if (V == 1) gBg ^= 1;
    const int rw = lane & 31;
    int preA[4], preB[4];
#pragma unroll
    for (int ks = 0; ks < 4; ++ks) {
        preA[ks] = rw * 128 + ((ks * 32 + (gAg << 4)) ^ ((rw & 7) << 4));
        preB[ks] = rw * 128 + ((ks * 32 + (gBg << 4)) ^ ((rw & 7) << 4));
    }

    const int rowA = t >> 3;
    const int colsw = ((t & 7) ^ ((t >> 3) & 7)) << 3;
    const ushort* gA0 = Ab + (size_t)(m0 + rowA) * Kstride + colsw;
    const ushort* gA1 = Ab + (size_t)(m0 + 128 + rowA) * Kstride + colsw;
    const ushort* gB0 = Bq + (size_t)rowA * Kstride + colsw;
    const ushort* gB1 = Bq + (size_t)(128 + rowA) * Kstride + colsw;
    const size_t jrow = (size_t)64 * Kstride;
    char* lb = smem + t * 16;

    f32x16 acc[4][2];
#pragma unroll
    for (int m = 0; m < 4; ++m)
#pragma unroll
        for (int n = 0; n < 2; ++n)
#pragma unroll
            for (int rix = 0; rix < 16; ++rix) acc[m][n][rix] = 0.f;

    for (int kt = 0; kt < NT; ++kt) {
        if (kt) {
            asm volatile("s_waitcnt lgkmcnt(0)" ::: "memory");
            __syncthreads();
        }
        gload_lds16(gA0, lb);             gload_lds16(gA0 + jrow, lb + 8192);
        gload_lds16(gA1, lb + 16384);     gload_lds16(gA1 + jrow, lb + 24576);
        gload_lds16(gB0, lb + 32768);     gload_lds16(gB0 + jrow, lb + 40960);
        gload_lds16(gB1, lb + 49152);     gload_lds16(gB1 + jrow, lb + 57344);
        gA0 += 64; gA1 += 64; gB0 += 64; gB1 += 64;
        asm volatile("s_waitcnt vmcnt(0)" ::: "memory");
        __syncthreads();

        const char* aB = smem + wr * 16384;
        const char* bB = smem + 32768 + bh * 16384 + (wc & 1) * 8192;
        bf16x8 af[4][4], bf[2][4];
#pragma unroll
        for (int m = 0; m < 4; ++m)
#pragma unroll
            for (int ks = 0; ks < 4; ++ks)
                af[m][ks] = *(const bf16x8*)(aB + m * 4096 + preA[ks]);
#pragma unroll
        for (int n = 0; n < 2; ++n)
#pragma unroll
            for (int ks = 0; ks < 4; ++ks) {
                bf16x8 bb = *(const bf16x8*)(bB + n * 4096 + preB[ks]);
                if (V == 2) bb = __builtin_shufflevector(bb, bb, 4, 5, 6, 7, 0, 1, 2, 3);
                bf[n][ks] = bb;
            }
#pragma unroll
        for (int m = 0; m < 4; ++m)
#pragma unroll
            for (int n = 0; n < 2; ++n)
#pragma unroll
                for (int ks = 0; ks < 4; ++ks)
                    acc[m][n] = __builtin_amdgcn_mfma_f32_32x32x16_bf16(
                        af[m][ks], bf[n][ks], acc[m][n], 0, 0, 0);
    }

    const float s = *scale_p;
    float* out = C2 + (size_t)blockIdx.x * 65536;
#pragma unroll
    for (int m = 0; m < 4; ++m)
#pragma unroll
        for (int n = 0; n < 2; ++n) {
            const int col = wc * 64 + n * 32 + (lane & 31);
            const int rbase = wr * 128 + m * 32 + 4 * (lane >> 5);
#pragma unroll
            for (int rix = 0; rix < 16; ++rix) {
                const int row = rbase + (rix & 3) + 8 * (rix >> 2);
                out[row * 256 + col] = s * acc[m][n][rix];
            }
        }
}

// fp32 oracle: out[i][r][c] = s * sum_k xh[(i*256+r)][k] * wq[c][k], k < Kloop
__global__ void ref32diag(const ushort* __restrict__ xh, const ushort* __restrict__ wq,
                          float* __restrict__ ref, const float* __restrict__ scale_p,
                          int Kstride, int Kloop) {
    const int b = blockIdx.x;        // 0..2047
    const int i = b >> 8;
    const int r = b & 255;
    const int c = threadIdx.x;
    const ushort* xr = xh + (size_t)(i * 256 + r) * Kstride;
    const ushort* wrow = wq + (size_t)c * Kstride;
    float acc = 0.f;
    for (int k = 0; k < Kloop; ++k)
        acc += bf16_f32(xr[k]) * bf16_f32(wrow[k]);  // bf16 products exact in fp32
    ref[(size_t)i * 65536 + r * 256 + c] = acc * (*scale_p);
}

__global__ void diag_zero(unsigned* cnt) {
    if (threadIdx.x < 4) cnt[threadIdx.x] = 0;
}

__global__ void cmp32diag(const float* __restrict__ ref, const float* __restrict__ c2,
                          unsigned* __restrict__ cnt) {
    const int e = blockIdx.x * 256 + threadIdx.x;   // 524288 elements
    const float rv = ref[e];
#pragma unroll
    for (int v = 0; v < 4; ++v) {
        float dv = c2[(size_t)v * 524288 + e];
        bool bad = !(fabsf(dv - rv) <= 0.0625f);    // NaN counts as bad
        unsigned long long m = __ballot(bad);
        if ((threadIdx.x & 63) == 0 && m)
            atomicAdd(&cnt[v], (unsigned)__popcll(m));
    }
}

__global__ void diag_spin(const unsigned* __restrict__ cnt) {
    unsigned mask = 0;
#pragma unroll
    for (int v = 0; v < 4; ++v)
        if (cnt[v]) mask |= 1u << v;
    const unsigned target_us = mask ? (600 + 200 * mask) : 500;
    const unsigned long long ticks = (unsigned long long)target_us * 100ull;  // 100 MHz
    const unsigned long long t0 = __builtin_amdgcn_s_memrealtime();
    while (__builtin_amdgcn_s_memrealtime() - t0 < ticks)
        __builtin_amdgcn_s_sleep(32);
}

// ---------- 128^2 fallback (validated round 2) ----------
template <bool ABF16>
__global__ __launch_bounds__(256) void qgemm(const void* __restrict__ Aptr,
                                             const ushort* __restrict__ Bq,
                                             float* __restrict__ C,
                                             const float* __restrict__ scale_p,
                                             int M, int N, int K) {
    __shared__ __align__(16) ushort sA[128 * 64];
    __shared__ __align__(16) ushort sB[128 * 64];

    const int t = threadIdx.x;
    const int lane = t & 63;
    const int w = t >> 6;
    const int wr = w >> 1, wc = w & 1;

    const int nwg = gridDim.x;
    int wg = blockIdx.x;
    if ((nwg & 7) == 0) wg = (wg & 7) * (nwg >> 3) + (wg >> 3);
    const int MT = M >> 7;
    const int mt = wg % MT;
    const int nt = wg / MT;
    const int m0 = mt * 128, n0 = nt * 128;

    const ushort* Ab = (const ushort*)Aptr;
    const float* Af = (const float*)Aptr;

    f32x4 zero = {0.f, 0.f, 0.f, 0.f};
    f32x4 acc[4][4];
#pragma unroll
    for (int m = 0; m < 4; ++m)
#pragma unroll
        for (int n = 0; n < 4; ++n) acc[m][n] = zero;

    for (int k0 = 0; k0 < K; k0 += 64) {
#pragma unroll
        for (int i = 0; i < 4; ++i) {
            int e = i * 2048 + t * 8;
            int r = e >> 6, c8 = (e >> 3) & 7;
            int srcc = (c8 ^ (r & 7)) * 8;
            gload_lds16(Bq + (size_t)(n0 + r) * K + (k0 + srcc), &sB[e]);
        }
        if constexpr (ABF16) {
#pragma unroll
            for (int i = 0; i < 4; ++i) {
                int e = i * 2048 + t * 8;
                int r = e >> 6, c8 = (e >> 3) & 7;
                int srcc = (c8 ^ (r & 7)) * 8;
                gload_lds16(Ab + (size_t)(m0 + r) * K + (k0 + srcc), &sA[e]);
            }
        } else {
#pragma unroll
            for (int i = 0; i < 4; ++i) {
                int e = i * 2048 + t * 8;
                int r = e >> 6, c = e & 63;
                const float* src = Af + (size_t)(m0 + r) * K + (k0 + c);
                float4 v0 = *(const float4*)src;
                float4 v1 = *(const float4*)(src + 4);
                bf16x8 pk;
                pk[0] = (short)f32_bf16_rne(v0.x); pk[1] = (short)f32_bf16_rne(v0.y);
                pk[2] = (short)f32_bf16_rne(v0.z); pk[3] = (short)f32_bf16_rne(v0.w);
                pk[4] = (short)f32_bf16_rne(v1.x); pk[5] = (short)f32_bf16_rne(v1.y);
                pk[6] = (short)f32_bf16_rne(v1.z); pk[7] = (short)f32_bf16_rne(v1.w);
                int byte = (r * 128 + c * 2) ^ ((r & 7) << 4);
                *(bf16x8*)((char*)sA + byte) = pk;
            }
        }
        __syncthreads();

#pragma unroll
        for (int ks = 0; ks < 2; ++ks) {
            const int kk = ks * 32 + ((lane >> 4) << 3);
            bf16x8 afr[4], bfr[4];
#pragma unroll
            for (int m = 0; m < 4; ++m) {
                int r = wr * 64 + m * 16 + (lane & 15);
                int byte = (r * 128 + kk * 2) ^ ((r & 7) << 4);
                afr[m] = *(const bf16x8*)((const char*)sA + byte);
            }
#pragma unroll
            for (int n = 0; n < 4; ++n) {
                int r = wc * 64 + n * 16 + (lane & 15);
                int byte = (r * 128 + kk * 2) ^ ((r & 7) << 4);
                bfr[n] = *(const bf16x8*)((const char*)sB + byte);
            }
#pragma unroll
            for (int m = 0; m < 4; ++m)
#pragma unroll
                for (int n = 0; n < 4; ++n)
                    acc[m][n] = __builtin_amdgcn_mfma_f32_16x16x32_bf16(
                        afr[m], bfr[n], acc[m][n], 0, 0, 0);
        }
        __syncthreads();
    }

    const float s = *scale_p;
#pragma unroll
    for (int m = 0; m < 4; ++m)
#pragma unroll
        for (int n = 0; n < 4; ++n) {
            const int col = n0 + wc * 64 + n * 16 + (lane & 15);
            const int rbase = m0 + wr * 64 + m * 16 + ((lane >> 4) << 2);
#pragma unroll
            for (int j = 0; j < 4; ++j)
                C[(size_t)(rbase + j) * N + col] = s * acc[m][n][j];
        }
}

// ---------- last-resort naive path ----------
__global__ void naive_qgemm(const float* __restrict__ X, const float* __restrict__ W,
                            float* __restrict__ out, const float* __restrict__ scale_p,
                            int M) {
    const int col = blockIdx.x * 256 + threadIdx.x;
    const int row = blockIdx.y;
    const float s = *scale_p;
    const float inv = 1.0f / s;
    const float* xr = X + (size_t)row * IN_F;
    const float* wrow = W + (size_t)col * IN_F;
    float acc = 0.f;
    for (int k = 0; k < IN_F; ++k) {
        float q = fminf(fmaxf(rintf(wrow[k] * inv), -2.f), 2.f);
        acc += xr[k] * q;
    }
    out[(size_t)row * OUT_F + col] = acc * s;
}

extern "C" void kernel_launch(void* const* d_in, const int* in_sizes, int n_in,
                              void* d_out, int out_size, void* d_ws, size_t ws_size,
                              hipStream_t stream) {
    const float* x = (const float*)d_in[0];
    const float* W = (const float*)d_in[1];
    float* out = (float*)d_out;
    const int M = in_sizes[0] / IN_F;  // 8192
    const int K = IN_F, N = OUT_F;

    char* ws = (char*)d_ws;
    const size_t OFF_PART = 512;
    const size_t OFF_WQ = OFF_PART + 4096 * sizeof(float);
    const size_t WQ_BYTES = (size_t)N * K * sizeof(ushort);
    const size_t OFF_XH = OFF_WQ + WQ_BYTES;
    const size_t XH_BYTES = (size_t)M * K * sizeof(ushort);
    float* scale = (float*)(ws + 0);
    float* part = (float*)(ws + OFF_PART);
    ushort* wq = (ushort*)(ws + OFF_WQ);
    ushort* xh = (ushort*)(ws + OFF_XH);

    // diagnostic scratch (beyond main path)
    const size_t OFF_REF = (OFF_XH + XH_BYTES + 255) & ~(size_t)255;
    const size_t TILE_BYTES = (size_t)8 * 65536 * sizeof(float);  // 2 MB
    const size_t OFF_V = OFF_REF + TILE_BYTES;
    const size_t OFF_CNT = OFF_V + 4 * TILE_BYTES;
    const size_t OFF_END = OFF_CNT + 256;
    float* refp = (float*)(ws + OFF_REF);
    float* c2base = (float*)(ws + OFF_V);
    unsigned* cnt = (unsigned*)(ws + OFF_CNT);

    if (ws_size < OFF_WQ) return;

    if (ws_size >= OFF_XH + XH_BYTES && (M % 256) == 0 && (N % 256) == 0 &&
        (N * K) == 4096 * 4096) {
        const bool diag = (ws_size >= OFF_END);
        const int castBlocks = (M * K / 4) / 256;
        fused_reduce_cast<<<4096 + castBlocks, 256, 0, stream>>>(W, part, x, xh);
        reduce_abs2<<<1, 256, 0, stream>>>(part, scale);
        quantize_w<<<(N * K / 4) / 256, 256, 0, stream>>>(W, wq, scale);

        if (diag) {
            diag_zero<<<1, 64, 0, stream>>>(cnt);
            const int KL = 512;
            (void)hipFuncSetAttribute((const void*)qgemm32diag<0>,
                hipFuncAttributeMaxDynamicSharedMemorySize, 65536);
            (void)hipFuncSetAttribute((const void*)qgemm32diag<1>,
                hipFuncAttributeMaxDynamicSharedMemorySize, 65536);
            (void)hipFuncSetAttribute((const void*)qgemm32diag<2>,
                hipFuncAttributeMaxDynamicSharedMemorySize, 65536);
            (void)hipFuncSetAttribute((const void*)qgemm32diag<3>,
                hipFuncAttributeMaxDynamicSharedMemorySize, 65536);
            qgemm32diag<0><<<8, 512, 65536, stream>>>(xh, wq, c2base + 0 * 524288, scale, K, KL);
            qgemm32diag<1><<<8, 512, 65536, stream>>>(xh, wq, c2base + 1 * 524288, scale, K, KL);
            qgemm32diag<2><<<8, 512, 65536, stream>>>(xh, wq, c2base + 2 * 524288, scale, K, KL);
            qgemm32diag<3><<<8, 512, 65536, stream>>>(xh, wq, c2base + 3 * 524288, scale, K, KL);
            ref32diag<<<2048, 256, 0, stream>>>(xh, wq, refp, scale, K, KL);
        }

        (void)hipFuncSetAttribute((const void*)qgemm256,
                                  hipFuncAttributeMaxDynamicSharedMemorySize,
                                  131072);
        qgemm256<<<(M / 256) * (N / 256), 512, 131072, stream>>>(
            xh, wq, out, scale, M, N, K);

        if (diag) {
            cmp32diag<<<2048, 256, 0, stream>>>(refp, c2base, cnt);
            diag_spin<<<1, 64, 0, stream>>>(cnt);
        }
    } else if (ws_size >= OFF_XH + XH_BYTES) {
        reduce_abs1<<<4096, 256, 0, stream>>>(W, part);
        reduce_abs2<<<1, 256, 0, stream>>>(part, scale);
        quantize_w<<<(N * K / 4) / 256, 256, 0, stream>>>(W, wq, scale);
        cast_x<<<(M * K / 4) / 256, 256, 0, stream>>>(x, xh);
        qgemm<true><<<(M / 128) * (N / 128), 256, 0, stream>>>(xh, wq, out, scale, M, N, K);
    } else if (ws_size >= OFF_WQ + WQ_BYTES) {
        reduce_abs1<<<4096, 256, 0, stream>>>(W, part);
        reduce_abs2<<<1, 256, 0, stream>>>(part, scale);
        quantize_w<<<(N * K / 4) / 256, 256, 0, stream>>>(W, wq, scale);
        qgemm<false><<<(M / 128) * (N / 128), 256, 0, stream>>>(x, wq, out, scale, M, N, K);
    } else {
        reduce_abs1<<<4096, 256, 0, stream>>>(W, part);
        reduce_abs2<<<1, 256, 0, stream>>>(part, scale);
        naive_qgemm<<<dim3(N / 256, M), 256, 0, stream>>>(x, W, out, scale, M);
    }
}

// Round 16
// 341.861 us; speedup vs baseline: 13.7569x; 13.7569x over previous
//
#include <hip/hip_runtime.h>
#include <cstdint>
#include <cstddef>

#define IN_F 4096
#define OUT_F 4096

typedef __attribute__((ext_vector_type(8))) short bf16x8;
typedef __attribute__((ext_vector_type(4))) float f32x4;
typedef __attribute__((ext_vector_type(16))) float f32x16;

__device__ __forceinline__ ushort f32_bf16_rne(float f) {
    uint32_t u = __builtin_bit_cast(uint32_t, f);
    uint32_t r = (u + 0x7FFFu + ((u >> 16) & 1u)) >> 16;
    return (ushort)r;
}

__device__ __forceinline__ void gload_lds16(const void* g, void* l) {
    __builtin_amdgcn_global_load_lds(
        (const __attribute__((address_space(1))) uint32_t*)g,
        (__attribute__((address_space(3))) uint32_t*)l,
        16, 0, 0);
}

// ---------- fused prologue (validated R14) ----------
__global__ void fused_reduce_cast(const float* __restrict__ W,
                                  float* __restrict__ part,
                                  const float* __restrict__ X,
                                  ushort* __restrict__ xh) {
    const int t = threadIdx.x;
    if (blockIdx.x < 4096) {
        __shared__ float sm[256];
        const int b = blockIdx.x;
        const float* p = W + (size_t)b * 4096;
        float s = 0.f;
#pragma unroll
        for (int j = 0; j < 16; ++j) s += fabsf(p[t + 256 * j]);
        sm[t] = s;
        __syncthreads();
        for (int w = 128; w > 0; w >>= 1) {
            if (t < w) sm[t] += sm[t + w];
            __syncthreads();
        }
        if (t == 0) part[b] = sm[0];
    } else {
        const int i = (blockIdx.x - 4096) * 256 + t;
        float4 v = ((const float4*)X)[i];
        ushort4 o;
        o.x = f32_bf16_rne(v.x); o.y = f32_bf16_rne(v.y);
        o.z = f32_bf16_rne(v.z); o.w = f32_bf16_rne(v.w);
        ((ushort4*)xh)[i] = o;
    }
}

__global__ void reduce_abs1(const float* __restrict__ W, float* __restrict__ part) {
    __shared__ float sm[256];
    const int b = blockIdx.x, t = threadIdx.x;
    const float* p = W + (size_t)b * 4096;
    float s = 0.f;
#pragma unroll
    for (int j = 0; j < 16; ++j) s += fabsf(p[t + 256 * j]);
    sm[t] = s;
    __syncthreads();
    for (int w = 128; w > 0; w >>= 1) {
        if (t < w) sm[t] += sm[t + w];
        __syncthreads();
    }
    if (t == 0) part[b] = sm[0];
}

__global__ void reduce_abs2(const float* __restrict__ part, float* __restrict__ scale) {
    __shared__ float sm[256];
    const int t = threadIdx.x;
    float s = 0.f;
#pragma unroll
    for (int j = 0; j < 16; ++j) s += part[t + 256 * j];
    sm[t] = s;
    __syncthreads();
    for (int w = 128; w > 0; w >>= 1) {
        if (t < w) sm[t] += sm[t + w];
        __syncthreads();
    }
    if (t == 0) {
        float m = sm[0] / 16777216.0f;
        *scale = fmaxf(m, 1e-8f);
    }
}

__global__ void quantize_w(const float* __restrict__ W, ushort* __restrict__ wq,
                           const float* __restrict__ scale_p) {
    const int i = blockIdx.x * 256 + threadIdx.x;
    const float s = *scale_p;
    float4 v = ((const float4*)W)[i];
    float q0 = fminf(fmaxf(rintf(v.x / s), -2.f), 2.f);
    float q1 = fminf(fmaxf(rintf(v.y / s), -2.f), 2.f);
    float q2 = fminf(fmaxf(rintf(v.z / s), -2.f), 2.f);
    float q3 = fminf(fmaxf(rintf(v.w / s), -2.f), 2.f);
    ushort4 o;
    o.x = f32_bf16_rne(q0); o.y = f32_bf16_rne(q1);
    o.z = f32_bf16_rne(q2); o.w = f32_bf16_rne(q3);
    ((ushort4*)wq)[i] = o;
}

__global__ void cast_x(const float* __restrict__ X, ushort* __restrict__ xh) {
    const int i = blockIdx.x * 256 + threadIdx.x;
    float4 v = ((const float4*)X)[i];
    ushort4 o;
    o.x = f32_bf16_rne(v.x); o.y = f32_bf16_rne(v.y);
    o.z = f32_bf16_rne(v.z); o.w = f32_bf16_rne(v.w);
    ((ushort4*)xh)[i] = o;
}

// ======= 256x256 GEMM: R12 8-phase skeleton + 32x32x16 MFMA (R16) ==========
// C = scale * (A @ B^T).  A:[M][K] bf16, B:[N][K] bf16 (both K-contiguous).
// 512 threads = 8 waves (2M x 4N); per-wave 128x64 output = 4m x 2n frags of
// 32x32 (f32x16 acc each, 128 AGPRs).  LDS 128 KiB: 2 K-tile buffers x
// {A0,A1,B0,B1} 16-KiB halves, XOR-swizzled (byte ^= (r&7)<<4) via
// pre-swizzled global source + swizzled ds_read (rule #21).
//
// 32x32 layout = R15-diag V0, HW-verified vs fp32 oracle (mask=14 decode):
//   A,B operand: row = lane&31, k = 8*(lane>>5)+j  (pre[] below)
//   C/D: col = lane&31, row = (reg&3) + 8*(reg>>2) + 4*(lane>>5)  (m74/m101)
// Rationale: 32x32x16 ceiling 2495 TF vs 16x16x32's 2176 (m119) at identical
// LDS traffic; half the MFMA instructions.  R9's failure was the R8 skeleton
// (cross-tile register read-ahead); R12's skeleton reads+consumes frags in
// the SAME phase after lgkmcnt(0) -- no cross-tile register carrying.
//
// Phases (reads 12/8/4/0, schedule byte-identical to validated R12):
//  P1: read b[0]+a[0..1] | stage B0(kt+1,nxt) | bar | lgkm0 | Q00 | bar
//  P2: read a[2..3]      | stage B1(kt+1,nxt) | bar | lgkm0 | Q10 | bar
//  P3: read b[1]         | stage A0(kt+2,cur) | bar | lgkm0 | Q01 | bar
//  P4:                   | stage A1(kt+2,cur) | vmcnt(4) | bar | lgkm0 | Q11 | bar
// Tail: kt>=NT-2 -> vmcnt(0) (R6 lesson).
#define BK 64
#define BUF_BYTES 65536

__global__ __launch_bounds__(512, 2) void qgemm256(
        const ushort* __restrict__ Ab, const ushort* __restrict__ Bq,
        float* __restrict__ C, const float* __restrict__ scale_p,
        int M, int N, int K) {
    extern __shared__ __align__(16) char smem[];

    const int t = threadIdx.x;
    const int lane = t & 63;
    const int w = t >> 6;
    const int wr = w >> 2;   // 0..1 (M half)
    const int wc = w & 3;    // 0..3 (N quarter)
    const int bh = wc >> 1;  // B half

    // ---- 2D XCD-aware supertiling (validated R7: FETCH 541->197 MB) ----
    const int MT = M >> 8;
    const int NTiles = N >> 8;
    int mt, nt;
    if (MT == 32 && NTiles == 16 && gridDim.x == 512) {
        const int x = blockIdx.x & 7;
        const int j = blockIdx.x >> 3;
        const int jr = j & 31;
        const int r = j >> 5;
        mt = (x & 3) * 8 + (jr & 7);
        nt = r * 8 + (x >> 2) * 4 + (jr >> 3);
    } else {
        const int nwg = gridDim.x;
        int wg = blockIdx.x;
        if ((nwg & 7) == 0) wg = (wg & 7) * (nwg >> 3) + (wg >> 3);
        mt = wg % MT; nt = wg / MT;
    }
    const int m0 = mt << 8;
    const int n0 = nt << 8;

    const int NT = K / BK;

    // per-lane ds_read byte offsets (32x32 frag, diag-V0): logical byte
    // ks*32 + (lane>>5)*16 of row lane&31, swizzled; add frag*4096 above.
    const int rw = lane & 31;
    const int g16 = (lane >> 5) << 4;
    int pre[4];
#pragma unroll
    for (int ks = 0; ks < 4; ++ks)
        pre[ks] = rw * 128 + ((ks * 32 + g16) ^ ((rw & 7) << 4));

    // ---- incrementing stage pointers (swizzled source, linear LDS dest) ----
    const int rowA = t >> 3;                                // 0..63
    const int colsw = ((t & 7) ^ ((t >> 3) & 7)) << 3;      // swizzled col (elems)
    const ushort* gA0 = Ab + (size_t)(m0 + rowA) * K + colsw;
    const ushort* gA1 = Ab + (size_t)(m0 + 128 + rowA) * K + colsw;
    const ushort* gB0 = Bq + (size_t)(n0 + rowA) * K + colsw;
    const ushort* gB1 = Bq + (size_t)(n0 + 128 + rowA) * K + colsw;
    const size_t jrow = (size_t)64 * K;                     // +64 rows
    char* lb = smem + t * 16;

    auto stA0 = [&](uint32_t par) {
        gload_lds16(gA0,        lb + par);
        gload_lds16(gA0 + jrow, lb + par + 8192);
        gA0 += 64;
    };
    auto stA1 = [&](uint32_t par) {
        gload_lds16(gA1,        lb + par + 16384);
        gload_lds16(gA1 + jrow, lb + par + 24576);
        gA1 += 64;
    };
    auto stB0 = [&](uint32_t par) {
        gload_lds16(gB0,        lb + par + 32768);
        gload_lds16(gB0 + jrow, lb + par + 40960);
        gB0 += 64;
    };
    auto stB1 = [&](uint32_t par) {
        gload_lds16(gB1,        lb + par + 49152);
        gload_lds16(gB1 + jrow, lb + par + 57344);
        gB1 += 64;
    };

    const char* aBbase = smem + wr * 16384;                        // wave's A half
    const char* bBbase = smem + 32768 + bh * 16384 + (wc & 1) * 8192;  // wave's B strip

    f32x16 acc[4][2];
#pragma unroll
    for (int m = 0; m < 4; ++m)
#pragma unroll
        for (int n = 0; n < 2; ++n)
#pragma unroll
            for (int rix = 0; rix < 16; ++rix) acc[m][n][rix] = 0.f;

    // ---- prologue: tile0 all 4 halves + tile1 A halves; vmcnt(4) ----
    stB0(0); stB1(0); stA0(0); stA1(0);
    stA0(BUF_BYTES); stA1(BUF_BYTES);
    asm volatile("s_waitcnt vmcnt(4)");  // tile0 confirmed; A(1) in flight
    __builtin_amdgcn_s_barrier();

    for (int kt = 0; kt < NT; ++kt) {
        const uint32_t cur = (uint32_t)(kt & 1) * BUF_BYTES;
        const uint32_t nxt = cur ^ BUF_BYTES;
        const char* aB = aBbase + cur;
        const char* bB = bBbase + cur;

        bf16x8 af[4][4], bf[2][4];

        // -------- P1: read b[0] + a[0..1]; stage B0(kt+1); Q00 --------
#pragma unroll
        for (int ks = 0; ks < 4; ++ks)
            bf[0][ks] = *(const bf16x8*)(bB + pre[ks]);
#pragma unroll
        for (int m = 0; m < 2; ++m)
#pragma unroll
            for (int ks = 0; ks < 4; ++ks)
                af[m][ks] = *(const bf16x8*)(aB + m * 4096 + pre[ks]);
        if (kt + 1 < NT) stB0(nxt);
        __builtin_amdgcn_s_barrier();
        asm volatile("s_waitcnt lgkmcnt(0)");
        __builtin_amdgcn_s_setprio(1);
#pragma unroll
        for (int m = 0; m < 2; ++m)
#pragma unroll
            for (int ks = 0; ks < 4; ++ks)
                acc[m][0] = __builtin_amdgcn_mfma_f32_32x32x16_bf16(
                    af[m][ks], bf[0][ks], acc[m][0], 0, 0, 0);
        __builtin_amdgcn_s_setprio(0);
        __builtin_amdgcn_s_barrier();

        // -------- P2: read a[2..3]; stage B1(kt+1); Q10 --------
#pragma unroll
        for (int m = 2; m < 4; ++m)
#pragma unroll
            for (int ks = 0; ks < 4; ++ks)
                af[m][ks] = *(const bf16x8*)(aB + m * 4096 + pre[ks]);
        if (kt + 1 < NT) stB1(nxt);
        __builtin_amdgcn_s_barrier();
        asm volatile("s_waitcnt lgkmcnt(0)");
        __builtin_amdgcn_s_setprio(1);
#pragma unroll
        for (int m = 2; m < 4; ++m)
#pragma unroll
            for (int ks = 0; ks < 4; ++ks)
                acc[m][0] = __builtin_amdgcn_mfma_f32_32x32x16_bf16(
                    af[m][ks], bf[0][ks], acc[m][0], 0, 0, 0);
        __builtin_amdgcn_s_setprio(0);
        __builtin_amdgcn_s_barrier();

        // -------- P3: read b[1]; stage A0(kt+2); Q01 --------
#pragma unroll
        for (int ks = 0; ks < 4; ++ks)
            bf[1][ks] = *(const bf16x8*)(bB + 4096 + pre[ks]);
        if (kt + 2 < NT) stA0(cur);
        __builtin_amdgcn_s_barrier();
        asm volatile("s_waitcnt lgkmcnt(0)");
        __builtin_amdgcn_s_setprio(1);
#pragma unroll
        for (int m = 0; m < 2; ++m)
#pragma unroll
            for (int ks = 0; ks < 4; ++ks)
                acc[m][1] = __builtin_amdgcn_mfma_f32_32x32x16_bf16(
                    af[m][ks], bf[1][ks], acc[m][1], 0, 0, 0);
        __builtin_amdgcn_s_setprio(0);
        __builtin_amdgcn_s_barrier();

        // -------- P4: stage A1(kt+2); boundary vmcnt; Q11 --------
        if (kt + 2 < NT) stA1(cur);
        if (kt < NT - 2) {
            asm volatile("s_waitcnt vmcnt(4)");  // confirms through B1(kt+1)
        } else {
            asm volatile("s_waitcnt vmcnt(0)");  // tail drain (R6 lesson)
        }
        __builtin_amdgcn_s_barrier();
        asm volatile("s_waitcnt lgkmcnt(0)");
        __builtin_amdgcn_s_setprio(1);
#pragma unroll
        for (int m = 2; m < 4; ++m)
#pragma unroll
            for (int ks = 0; ks < 4; ++ks)
                acc[m][1] = __builtin_amdgcn_mfma_f32_32x32x16_bf16(
                    af[m][ks], bf[1][ks], acc[m][1], 0, 0, 0);
        __builtin_amdgcn_s_setprio(0);
        __builtin_amdgcn_s_barrier();
    }

    // ---- epilogue (diag-V0 verified): col=lane&31, row=(reg&3)+8*(reg>>2)+4*(lane>>5)
    const float s = *scale_p;
#pragma unroll
    for (int m = 0; m < 4; ++m)
#pragma unroll
        for (int n = 0; n < 2; ++n) {
            const int col = n0 + wc * 64 + n * 32 + (lane & 31);
            const int rbase = m0 + wr * 128 + m * 32 + 4 * (lane >> 5);
#pragma unroll
            for (int rix = 0; rix < 16; ++rix) {
                const int row = rbase + (rix & 3) + 8 * (rix >> 2);
                C[(size_t)row * N + col] = s * acc[m][n][rix];
            }
        }
}

// ---------- 128^2 fallback (validated round 2) ----------
template <bool ABF16>
__global__ __launch_bounds__(256) void qgemm(const void* __restrict__ Aptr,
                                             const ushort* __restrict__ Bq,
                                             float* __restrict__ C,
                                             const float* __restrict__ scale_p,
                                             int M, int N, int K) {
    __shared__ __align__(16) ushort sA[128 * 64];
    __shared__ __align__(16) ushort sB[128 * 64];

    const int t = threadIdx.x;
    const int lane = t & 63;
    const int w = t >> 6;
    const int wr = w >> 1, wc = w & 1;

    const int nwg = gridDim.x;
    int wg = blockIdx.x;
    if ((nwg & 7) == 0) wg = (wg & 7) * (nwg >> 3) + (wg >> 3);
    const int MT = M >> 7;
    const int mt = wg % MT;
    const int nt = wg / MT;
    const int m0 = mt * 128, n0 = nt * 128;

    const ushort* Ab = (const ushort*)Aptr;
    const float* Af = (const float*)Aptr;

    f32x4 zero = {0.f, 0.f, 0.f, 0.f};
    f32x4 acc[4][4];
#pragma unroll
    for (int m = 0; m < 4; ++m)
#pragma unroll
        for (int n = 0; n < 4; ++n) acc[m][n] = zero;

    for (int k0 = 0; k0 < K; k0 += 64) {
#pragma unroll
        for (int i = 0; i < 4; ++i) {
            int e = i * 2048 + t * 8;
            int r = e >> 6, c8 = (e >> 3) & 7;
            int srcc = (c8 ^ (r & 7)) * 8;
            gload_lds16(Bq + (size_t)(n0 + r) * K + (k0 + srcc), &sB[e]);
        }
        if constexpr (ABF16) {
#pragma unroll
            for (int i = 0; i < 4; ++i) {
                int e = i * 2048 + t * 8;
                int r = e >> 6, c8 = (e >> 3) & 7;
                int srcc = (c8 ^ (r & 7)) * 8;
                gload_lds16(Ab + (size_t)(m0 + r) * K + (k0 + srcc), &sA[e]);
            }
        } else {
#pragma unroll
            for (int i = 0; i < 4; ++i) {
                int e = i * 2048 + t * 8;
                int r = e >> 6, c = e & 63;
                const float* src = Af + (size_t)(m0 + r) * K + (k0 + c);
                float4 v0 = *(const float4*)src;
                float4 v1 = *(const float4*)(src + 4);
                bf16x8 pk;
                pk[0] = (short)f32_bf16_rne(v0.x); pk[1] = (short)f32_bf16_rne(v0.y);
                pk[2] = (short)f32_bf16_rne(v0.z); pk[3] = (short)f32_bf16_rne(v0.w);
                pk[4] = (short)f32_bf16_rne(v1.x); pk[5] = (short)f32_bf16_rne(v1.y);
                pk[6] = (short)f32_bf16_rne(v1.z); pk[7] = (short)f32_bf16_rne(v1.w);
                int byte = (r * 128 + c * 2) ^ ((r & 7) << 4);
                *(bf16x8*)((char*)sA + byte) = pk;
            }
        }
        __syncthreads();

#pragma unroll
        for (int ks = 0; ks < 2; ++ks) {
            const int kk = ks * 32 + ((lane >> 4) << 3);
            bf16x8 afr[4], bfr[4];
#pragma unroll
            for (int m = 0; m < 4; ++m) {
                int r = wr * 64 + m * 16 + (lane & 15);
                int byte = (r * 128 + kk * 2) ^ ((r & 7) << 4);
                afr[m] = *(const bf16x8*)((const char*)sA + byte);
            }
#pragma unroll
            for (int n = 0; n < 4; ++n) {
                int r = wc * 64 + n * 16 + (lane & 15);
                int byte = (r * 128 + kk * 2) ^ ((r & 7) << 4);
                bfr[n] = *(const bf16x8*)((const char*)sB + byte);
            }
#pragma unroll
            for (int m = 0; m < 4; ++m)
#pragma unroll
                for (int n = 0; n < 4; ++n)
                    acc[m][n] = __builtin_amdgcn_mfma_f32_16x16x32_bf16(
                        afr[m], bfr[n], acc[m][n], 0, 0, 0);
        }
        __syncthreads();
    }

    const float s = *scale_p;
#pragma unroll
    for (int m = 0; m < 4; ++m)
#pragma unroll
        for (int n = 0; n < 4; ++n) {
            const int col = n0 + wc * 64 + n * 16 + (lane & 15);
            const int rbase = m0 + wr * 64 + m * 16 + ((lane >> 4) << 2);
#pragma unroll
            for (int j = 0; j < 4; ++j)
                C[(size_t)(rbase + j) * N + col] = s * acc[m][n][j];
        }
}

// ---------- last-resort naive path ----------
__global__ void naive_qgemm(const float* __restrict__ X, const float* __restrict__ W,
                            float* __restrict__ out, const float* __restrict__ scale_p,
                            int M) {
    const int col = blockIdx.x * 256 + threadIdx.x;
    const int row = blockIdx.y;
    const float s = *scale_p;
    const float inv = 1.0f / s;
    const float* xr = X + (size_t)row * IN_F;
    const float* wrow = W + (size_t)col * IN_F;
    float acc = 0.f;
    for (int k = 0; k < IN_F; ++k) {
        float q = fminf(fmaxf(rintf(wrow[k] * inv), -2.f), 2.f);
        acc += xr[k] * q;
    }
    out[(size_t)row * OUT_F + col] = acc * s;
}

extern "C" void kernel_launch(void* const* d_in, const int* in_sizes, int n_in,
                              void* d_out, int out_size, void* d_ws, size_t ws_size,
                              hipStream_t stream) {
    const float* x = (const float*)d_in[0];
    const float* W = (const float*)d_in[1];
    float* out = (float*)d_out;
    const int M = in_sizes[0] / IN_F;  // 8192
    const int K = IN_F, N = OUT_F;

    char* ws = (char*)d_ws;
    const size_t OFF_PART = 512;
    const size_t OFF_WQ = OFF_PART + 4096 * sizeof(float);
    const size_t WQ_BYTES = (size_t)N * K * sizeof(ushort);
    const size_t OFF_XH = OFF_WQ + WQ_BYTES;
    const size_t XH_BYTES = (size_t)M * K * sizeof(ushort);
    float* scale = (float*)(ws + 0);
    float* part = (float*)(ws + OFF_PART);
    ushort* wq = (ushort*)(ws + OFF_WQ);
    ushort* xh = (ushort*)(ws + OFF_XH);

    if (ws_size < OFF_WQ) return;

    if (ws_size >= OFF_XH + XH_BYTES && (M % 256) == 0 && (N % 256) == 0 &&
        (N * K) == 4096 * 4096) {
        const int castBlocks = (M * K / 4) / 256;
        fused_reduce_cast<<<4096 + castBlocks, 256, 0, stream>>>(W, part, x, xh);
        reduce_abs2<<<1, 256, 0, stream>>>(part, scale);
        quantize_w<<<(N * K / 4) / 256, 256, 0, stream>>>(W, wq, scale);
        (void)hipFuncSetAttribute((const void*)qgemm256,
                                  hipFuncAttributeMaxDynamicSharedMemorySize,
                                  131072);
        qgemm256<<<(M / 256) * (N / 256), 512, 131072, stream>>>(
            xh, wq, out, scale, M, N, K);
    } else if (ws_size >= OFF_XH + XH_BYTES) {
        reduce_abs1<<<4096, 256, 0, stream>>>(W, part);
        reduce_abs2<<<1, 256, 0, stream>>>(part, scale);
        quantize_w<<<(N * K / 4) / 256, 256, 0, stream>>>(W, wq, scale);
        cast_x<<<(M * K / 4) / 256, 256, 0, stream>>>(x, xh);
        qgemm<true><<<(M / 128) * (N / 128), 256, 0, stream>>>(xh, wq, out, scale, M, N, K);
    } else if (ws_size >= OFF_WQ + WQ_BYTES) {
        reduce_abs1<<<4096, 256, 0, stream>>>(W, part);
        reduce_abs2<<<1, 256, 0, stream>>>(part, scale);
        quantize_w<<<(N * K / 4) / 256, 256, 0, stream>>>(W, wq, scale);
        qgemm<false><<<(M / 128) * (N / 128), 256, 0, stream>>>(x, wq, out, scale, M, N, K);
    } else {
        reduce_abs1<<<4096, 256, 0, stream>>>(W, part);
        reduce_abs2<<<1, 256, 0, stream>>>(part, scale);
        naive_qgemm<<<dim3(N / 256, M), 256, 0, stream>>>(x, W, out, scale, M);
    }
}

// Round 17
// 311.482 us; speedup vs baseline: 15.0987x; 1.0975x over previous
//
#include <hip/hip_runtime.h>
#include <cstdint>
#include <cstddef>

#define IN_F 4096
#define OUT_F 4096

typedef __attribute__((ext_vector_type(8))) short bf16x8;
typedef __attribute__((ext_vector_type(4))) float f32x4;

__device__ __forceinline__ ushort f32_bf16_rne(float f) {
    uint32_t u = __builtin_bit_cast(uint32_t, f);
    uint32_t r = (u + 0x7FFFu + ((u >> 16) & 1u)) >> 16;
    return (ushort)r;
}

__device__ __forceinline__ void gload_lds16(const void* g, void* l) {
    __builtin_amdgcn_global_load_lds(
        (const __attribute__((address_space(1))) uint32_t*)g,
        (__attribute__((address_space(3))) uint32_t*)l,
        16, 0, 0);
}

// ---------- fused prologue (validated R14) ----------
__global__ void fused_reduce_cast(const float* __restrict__ W,
                                  float* __restrict__ part,
                                  const float* __restrict__ X,
                                  ushort* __restrict__ xh) {
    const int t = threadIdx.x;
    if (blockIdx.x < 4096) {
        __shared__ float sm[256];
        const int b = blockIdx.x;
        const float* p = W + (size_t)b * 4096;
        float s = 0.f;
#pragma unroll
        for (int j = 0; j < 16; ++j) s += fabsf(p[t + 256 * j]);
        sm[t] = s;
        __syncthreads();
        for (int w = 128; w > 0; w >>= 1) {
            if (t < w) sm[t] += sm[t + w];
            __syncthreads();
        }
        if (t == 0) part[b] = sm[0];
    } else {
        const int i = (blockIdx.x - 4096) * 256 + t;
        float4 v = ((const float4*)X)[i];
        ushort4 o;
        o.x = f32_bf16_rne(v.x); o.y = f32_bf16_rne(v.y);
        o.z = f32_bf16_rne(v.z); o.w = f32_bf16_rne(v.w);
        ((ushort4*)xh)[i] = o;
    }
}

__global__ void reduce_abs1(const float* __restrict__ W, float* __restrict__ part) {
    __shared__ float sm[256];
    const int b = blockIdx.x, t = threadIdx.x;
    const float* p = W + (size_t)b * 4096;
    float s = 0.f;
#pragma unroll
    for (int j = 0; j < 16; ++j) s += fabsf(p[t + 256 * j]);
    sm[t] = s;
    __syncthreads();
    for (int w = 128; w > 0; w >>= 1) {
        if (t < w) sm[t] += sm[t + w];
        __syncthreads();
    }
    if (t == 0) part[b] = sm[0];
}

__global__ void reduce_abs2(const float* __restrict__ part, float* __restrict__ scale) {
    __shared__ float sm[256];
    const int t = threadIdx.x;
    float s = 0.f;
#pragma unroll
    for (int j = 0; j < 16; ++j) s += part[t + 256 * j];
    sm[t] = s;
    __syncthreads();
    for (int w = 128; w > 0; w >>= 1) {
        if (t < w) sm[t] += sm[t + w];
        __syncthreads();
    }
    if (t == 0) {
        float m = sm[0] / 16777216.0f;
        *scale = fmaxf(m, 1e-8f);
    }
}

__global__ void quantize_w(const float* __restrict__ W, ushort* __restrict__ wq,
                           const float* __restrict__ scale_p) {
    const int i = blockIdx.x * 256 + threadIdx.x;
    const float s = *scale_p;
    float4 v = ((const float4*)W)[i];
    float q0 = fminf(fmaxf(rintf(v.x / s), -2.f), 2.f);
    float q1 = fminf(fmaxf(rintf(v.y / s), -2.f), 2.f);
    float q2 = fminf(fmaxf(rintf(v.z / s), -2.f), 2.f);
    float q3 = fminf(fmaxf(rintf(v.w / s), -2.f), 2.f);
    ushort4 o;
    o.x = f32_bf16_rne(q0); o.y = f32_bf16_rne(q1);
    o.z = f32_bf16_rne(q2); o.w = f32_bf16_rne(q3);
    ((ushort4*)wq)[i] = o;
}

__global__ void cast_x(const float* __restrict__ X, ushort* __restrict__ xh) {
    const int i = blockIdx.x * 256 + threadIdx.x;
    float4 v = ((const float4*)X)[i];
    ushort4 o;
    o.x = f32_bf16_rne(v.x); o.y = f32_bf16_rne(v.y);
    o.z = f32_bf16_rne(v.z); o.w = f32_bf16_rne(v.w);
    ((ushort4*)xh)[i] = o;
}

// ======= 256x256 GEMM: R12 8-phase, 16x16x32 MFMA (best validated) =========
// C = scale * (A @ B^T).  A:[M][K] bf16, B:[N][K] bf16 (both K-contiguous).
// 512 threads = 8 waves (2M x 4N); per-wave 128x64 output (acc[8][4], AGPR).
// LDS 128 KiB: 2 K-tile buffers x {A0,A1,B0,B1} 16-KiB halves, XOR-swizzled
// (byte ^= (r&7)<<4) via pre-swizzled global source + swizzled ds_read
// (both-sides, rule #21).  16x16 frag reads span only 16 rows per b128 ->
// conflict-free (R16's 32x32 spans 32 rows -> unavoidable 4-way, reverted).
//
// Phases (reads 12/8/4/0):
//  P1: read b01+a0 | stage B0(kt+1,nxt) | bar | lgkm0 | Q00 | bar
//  P2: read a1     | stage B1(kt+1,nxt) | bar | lgkm0 | Q10 | bar
//  P3: read b23    | stage A0(kt+2,cur) | bar | lgkm0 | Q01 | bar
//  P4:             | stage A1(kt+2,cur) | vmcnt(4) | bar | lgkm0 | Q11 | bar
// WAR: every stage lands >=1 lgkm-drained barrier after its region's last
// read.  RAW: vmcnt(4)@P4 confirms through B1(kt+1).  Tail: kt>=NT-2 ->
// vmcnt(0) (R6 lesson).
#define BK 64
#define BUF_BYTES 65536

__global__ __launch_bounds__(512, 2) void qgemm256(
        const ushort* __restrict__ Ab, const ushort* __restrict__ Bq,
        float* __restrict__ C, const float* __restrict__ scale_p,
        int M, int N, int K) {
    extern __shared__ __align__(16) char smem[];

    const int t = threadIdx.x;
    const int lane = t & 63;
    const int w = t >> 6;
    const int wr = w >> 2;
    const int wc = w & 3;
    const int bh = wc >> 1;

    // ---- 2D XCD-aware supertiling (validated R7: FETCH 541->197 MB) ----
    const int MT = M >> 8;
    const int NTiles = N >> 8;
    int mt, nt;
    if (MT == 32 && NTiles == 16 && gridDim.x == 512) {
        const int x = blockIdx.x & 7;
        const int j = blockIdx.x >> 3;
        const int jr = j & 31;
        const int r = j >> 5;
        mt = (x & 3) * 8 + (jr & 7);
        nt = r * 8 + (x >> 2) * 4 + (jr >> 3);
    } else {
        const int nwg = gridDim.x;
        int wg = blockIdx.x;
        if ((nwg & 7) == 0) wg = (wg & 7) * (nwg >> 3) + (wg >> 3);
        mt = wg % MT; nt = wg / MT;
    }
    const int m0 = mt << 8;
    const int n0 = nt << 8;

    const int NT = K / BK;

    int pre[2];
#pragma unroll
    for (int ks = 0; ks < 2; ++ks)
        pre[ks] = (lane & 15) * 128 +
                  (((ks * 64) + ((lane >> 4) * 16)) ^ ((lane & 7) << 4));

    const int rowA = t >> 3;
    const int colsw = ((t & 7) ^ ((t >> 3) & 7)) << 3;
    const ushort* gA0 = Ab + (size_t)(m0 + rowA) * K + colsw;
    const ushort* gA1 = Ab + (size_t)(m0 + 128 + rowA) * K + colsw;
    const ushort* gB0 = Bq + (size_t)(n0 + rowA) * K + colsw;
    const ushort* gB1 = Bq + (size_t)(n0 + 128 + rowA) * K + colsw;
    const size_t jrow = (size_t)64 * K;
    char* lb = smem + t * 16;

    auto stA0 = [&](uint32_t par) {
        gload_lds16(gA0,        lb + par);
        gload_lds16(gA0 + jrow, lb + par + 8192);
        gA0 += 64;
    };
    auto stA1 = [&](uint32_t par) {
        gload_lds16(gA1,        lb + par + 16384);
        gload_lds16(gA1 + jrow, lb + par + 24576);
        gA1 += 64;
    };
    auto stB0 = [&](uint32_t par) {
        gload_lds16(gB0,        lb + par + 32768);
        gload_lds16(gB0 + jrow, lb + par + 40960);
        gB0 += 64;
    };
    auto stB1 = [&](uint32_t par) {
        gload_lds16(gB1,        lb + par + 49152);
        gload_lds16(gB1 + jrow, lb + par + 57344);
        gB1 += 64;
    };

    const char* aBbase = smem + wr * 16384;
    const char* bBbase = smem + 32768 + bh * 16384 + (wc & 1) * 8192;

    f32x4 acc[8][4];
#pragma unroll
    for (int m = 0; m < 8; ++m)
#pragma unroll
        for (int n = 0; n < 4; ++n) acc[m][n] = (f32x4){0.f, 0.f, 0.f, 0.f};

    stB0(0); stB1(0); stA0(0); stA1(0);
    stA0(BUF_BYTES); stA1(BUF_BYTES);
    asm volatile("s_waitcnt vmcnt(4)");
    __builtin_amdgcn_s_barrier();

    for (int kt = 0; kt < NT; ++kt) {
        const uint32_t cur = (uint32_t)(kt & 1) * BUF_BYTES;
        const uint32_t nxt = cur ^ BUF_BYTES;
        const char* aB = aBbase + cur;
        const char* bB = bBbase + cur;

        bf16x8 a0[4][2], a1[4][2], b01[2][2], b23[2][2];

        // -------- P1: read b01 + a0; stage B0(kt+1); Q00 --------
#pragma unroll
        for (int n = 0; n < 2; ++n)
#pragma unroll
            for (int ks = 0; ks < 2; ++ks)
                b01[n][ks] = *(const bf16x8*)(bB + n * 2048 + pre[ks]);
#pragma unroll
        for (int m = 0; m < 4; ++m)
#pragma unroll
            for (int ks = 0; ks < 2; ++ks)
                a0[m][ks] = *(const bf16x8*)(aB + m * 2048 + pre[ks]);
        if (kt + 1 < NT) stB0(nxt);
        __builtin_amdgcn_s_barrier();
        asm volatile("s_waitcnt lgkmcnt(0)");
        __builtin_amdgcn_s_setprio(1);
#pragma unroll
        for (int m = 0; m < 4; ++m)
#pragma unroll
            for (int n = 0; n < 2; ++n)
#pragma unroll
                for (int ks = 0; ks < 2; ++ks)
                    acc[m][n] = __builtin_amdgcn_mfma_f32_16x16x32_bf16(
                        a0[m][ks], b01[n][ks], acc[m][n], 0, 0, 0);
        __builtin_amdgcn_s_setprio(0);
        __builtin_amdgcn_s_barrier();

        // -------- P2: read a1; stage B1(kt+1); Q10 --------
#pragma unroll
        for (int m = 0; m < 4; ++m)
#pragma unroll
            for (int ks = 0; ks < 2; ++ks)
                a1[m][ks] = *(const bf16x8*)(aB + (m + 4) * 2048 + pre[ks]);
        if (kt + 1 < NT) stB1(nxt);
        __builtin_amdgcn_s_barrier();
        asm volatile("s_waitcnt lgkmcnt(0)");
        __builtin_amdgcn_s_setprio(1);
#pragma unroll
        for (int m = 0; m < 4; ++m)
#pragma unroll
            for (int n = 0; n < 2; ++n)
#pragma unroll
                for (int ks = 0; ks < 2; ++ks)
                    acc[m + 4][n] = __builtin_amdgcn_mfma_f32_16x16x32_bf16(
                        a1[m][ks], b01[n][ks], acc[m + 4][n], 0, 0, 0);
        __builtin_amdgcn_s_setprio(0);
        __builtin_amdgcn_s_barrier();

        // -------- P3: read b23; stage A0(kt+2); Q01 --------
#pragma unroll
        for (int n = 0; n < 2; ++n)
#pragma unroll
            for (int ks = 0; ks < 2; ++ks)
                b23[n][ks] = *(const bf16x8*)(bB + (n + 2) * 2048 + pre[ks]);
        if (kt + 2 < NT) stA0(cur);
        __builtin_amdgcn_s_barrier();
        asm volatile("s_waitcnt lgkmcnt(0)");
        __builtin_amdgcn_s_setprio(1);
#pragma unroll
        for (int m = 0; m < 4; ++m)
#pragma unroll
            for (int n = 0; n < 2; ++n)
#pragma unroll
                for (int ks = 0; ks < 2; ++ks)
                    acc[m][n + 2] = __builtin_amdgcn_mfma_f32_16x16x32_bf16(
                        a0[m][ks], b23[n][ks], acc[m][n + 2], 0, 0, 0);
        __builtin_amdgcn_s_setprio(0);
        __builtin_amdgcn_s_barrier();

        // -------- P4: stage A1(kt+2); boundary vmcnt; Q11 --------
        if (kt + 2 < NT) stA1(cur);
        if (kt < NT - 2) {
            asm volatile("s_waitcnt vmcnt(4)");
        } else {
            asm volatile("s_waitcnt vmcnt(0)");
        }
        __builtin_amdgcn_s_barrier();
        asm volatile("s_waitcnt lgkmcnt(0)");
        __builtin_amdgcn_s_setprio(1);
#pragma unroll
        for (int m = 0; m < 4; ++m)
#pragma unroll
            for (int n = 0; n < 2; ++n)
#pragma unroll
                for (int ks = 0; ks < 2; ++ks)
                    acc[m + 4][n + 2] = __builtin_amdgcn_mfma_f32_16x16x32_bf16(
                        a1[m][ks], b23[n][ks], acc[m + 4][n + 2], 0, 0, 0);
        __builtin_amdgcn_s_setprio(0);
        __builtin_amdgcn_s_barrier();
    }

    const float s = *scale_p;
#pragma unroll
    for (int m = 0; m < 8; ++m)
#pragma unroll
        for (int n = 0; n < 4; ++n) {
            const int col = n0 + wc * 64 + n * 16 + (lane & 15);
            const int rbase = m0 + wr * 128 + m * 16 + ((lane >> 4) << 2);
#pragma unroll
            for (int j = 0; j < 4; ++j)
                C[(size_t)(rbase + j) * N + col] = s * acc[m][n][j];
        }
}

// ---------- 128^2 fallback (validated round 2) ----------
template <bool ABF16>
__global__ __launch_bounds__(256) void qgemm(const void* __restrict__ Aptr,
                                             const ushort* __restrict__ Bq,
                                             float* __restrict__ C,
                                             const float* __restrict__ scale_p,
                                             int M, int N, int K) {
    __shared__ __align__(16) ushort sA[128 * 64];
    __shared__ __align__(16) ushort sB[128 * 64];

    const int t = threadIdx.x;
    const int lane = t & 63;
    const int w = t >> 6;
    const int wr = w >> 1, wc = w & 1;

    const int nwg = gridDim.x;
    int wg = blockIdx.x;
    if ((nwg & 7) == 0) wg = (wg & 7) * (nwg >> 3) + (wg >> 3);
    const int MT = M >> 7;
    const int mt = wg % MT;
    const int nt = wg / MT;
    const int m0 = mt * 128, n0 = nt * 128;

    const ushort* Ab = (const ushort*)Aptr;
    const float* Af = (const float*)Aptr;

    f32x4 zero = {0.f, 0.f, 0.f, 0.f};
    f32x4 acc[4][4];
#pragma unroll
    for (int m = 0; m < 4; ++m)
#pragma unroll
        for (int n = 0; n < 4; ++n) acc[m][n] = zero;

    for (int k0 = 0; k0 < K; k0 += 64) {
#pragma unroll
        for (int i = 0; i < 4; ++i) {
            int e = i * 2048 + t * 8;
            int r = e >> 6, c8 = (e >> 3) & 7;
            int srcc = (c8 ^ (r & 7)) * 8;
            gload_lds16(Bq + (size_t)(n0 + r) * K + (k0 + srcc), &sB[e]);
        }
        if constexpr (ABF16) {
#pragma unroll
            for (int i = 0; i < 4; ++i) {
                int e = i * 2048 + t * 8;
                int r = e >> 6, c8 = (e >> 3) & 7;
                int srcc = (c8 ^ (r & 7)) * 8;
                gload_lds16(Ab + (size_t)(m0 + r) * K + (k0 + srcc), &sA[e]);
            }
        } else {
#pragma unroll
            for (int i = 0; i < 4; ++i) {
                int e = i * 2048 + t * 8;
                int r = e >> 6, c = e & 63;
                const float* src = Af + (size_t)(m0 + r) * K + (k0 + c);
                float4 v0 = *(const float4*)src;
                float4 v1 = *(const float4*)(src + 4);
                bf16x8 pk;
                pk[0] = (short)f32_bf16_rne(v0.x); pk[1] = (short)f32_bf16_rne(v0.y);
                pk[2] = (short)f32_bf16_rne(v0.z); pk[3] = (short)f32_bf16_rne(v0.w);
                pk[4] = (short)f32_bf16_rne(v1.x); pk[5] = (short)f32_bf16_rne(v1.y);
                pk[6] = (short)f32_bf16_rne(v1.z); pk[7] = (short)f32_bf16_rne(v1.w);
                int byte = (r * 128 + c * 2) ^ ((r & 7) << 4);
                *(bf16x8*)((char*)sA + byte) = pk;
            }
        }
        __syncthreads();

#pragma unroll
        for (int ks = 0; ks < 2; ++ks) {
            const int kk = ks * 32 + ((lane >> 4) << 3);
            bf16x8 afr[4], bfr[4];
#pragma unroll
            for (int m = 0; m < 4; ++m) {
                int r = wr * 64 + m * 16 + (lane & 15);
                int byte = (r * 128 + kk * 2) ^ ((r & 7) << 4);
                afr[m] = *(const bf16x8*)((const char*)sA + byte);
            }
#pragma unroll
            for (int n = 0; n < 4; ++n) {
                int r = wc * 64 + n * 16 + (lane & 15);
                int byte = (r * 128 + kk * 2) ^ ((r & 7) << 4);
                bfr[n] = *(const bf16x8*)((const char*)sB + byte);
            }
#pragma unroll
            for (int m = 0; m < 4; ++m)
#pragma unroll
                for (int n = 0; n < 4; ++n)
                    acc[m][n] = __builtin_amdgcn_mfma_f32_16x16x32_bf16(
                        afr[m], bfr[n], acc[m][n], 0, 0, 0);
        }
        __syncthreads();
    }

    const float s = *scale_p;
#pragma unroll
    for (int m = 0; m < 4; ++m)
#pragma unroll
        for (int n = 0; n < 4; ++n) {
            const int col = n0 + wc * 64 + n * 16 + (lane & 15);
            const int rbase = m0 + wr * 64 + m * 16 + ((lane >> 4) << 2);
#pragma unroll
            for (int j = 0; j < 4; ++j)
                C[(size_t)(rbase + j) * N + col] = s * acc[m][n][j];
        }
}

// ---------- last-resort naive path ----------
__global__ void naive_qgemm(const float* __restrict__ X, const float* __restrict__ W,
                            float* __restrict__ out, const float* __restrict__ scale_p,
                            int M) {
    const int col = blockIdx.x * 256 + threadIdx.x;
    const int row = blockIdx.y;
    const float s = *scale_p;
    const float inv = 1.0f / s;
    const float* xr = X + (size_t)row * IN_F;
    const float* wrow = W + (size_t)col * IN_F;
    float acc = 0.f;
    for (int k = 0; k < IN_F; ++k) {
        float q = fminf(fmaxf(rintf(wrow[k] * inv), -2.f), 2.f);
        acc += xr[k] * q;
    }
    out[(size_t)row * OUT_F + col] = acc * s;
}

extern "C" void kernel_launch(void* const* d_in, const int* in_sizes, int n_in,
                              void* d_out, int out_size, void* d_ws, size_t ws_size,
                              hipStream_t stream) {
    const float* x = (const float*)d_in[0];
    const float* W = (const float*)d_in[1];
    float* out = (float*)d_out;
    const int M = in_sizes[0] / IN_F;  // 8192
    const int K = IN_F, N = OUT_F;

    char* ws = (char*)d_ws;
    const size_t OFF_PART = 512;
    const size_t OFF_WQ = OFF_PART + 4096 * sizeof(float);
    const size_t WQ_BYTES = (size_t)N * K * sizeof(ushort);
    const size_t OFF_XH = OFF_WQ + WQ_BYTES;
    const size_t XH_BYTES = (size_t)M * K * sizeof(ushort);
    float* scale = (float*)(ws + 0);
    float* part = (float*)(ws + OFF_PART);
    ushort* wq = (ushort*)(ws + OFF_WQ);
    ushort* xh = (ushort*)(ws + OFF_XH);

    if (ws_size < OFF_WQ) return;

    if (ws_size >= OFF_XH + XH_BYTES && (M % 256) == 0 && (N % 256) == 0 &&
        (N * K) == 4096 * 4096) {
        const int castBlocks = (M * K / 4) / 256;
        fused_reduce_cast<<<4096 + castBlocks, 256, 0, stream>>>(W, part, x, xh);
        reduce_abs2<<<1, 256, 0, stream>>>(part, scale);
        quantize_w<<<(N * K / 4) / 256, 256, 0, stream>>>(W, wq, scale);
        (void)hipFuncSetAttribute((const void*)qgemm256,
                                  hipFuncAttributeMaxDynamicSharedMemorySize,
                                  131072);
        qgemm256<<<(M / 256) * (N / 256), 512, 131072, stream>>>(
            xh, wq, out, scale, M, N, K);
    } else if (ws_size >= OFF_XH + XH_BYTES) {
        reduce_abs1<<<4096, 256, 0, stream>>>(W, part);
        reduce_abs2<<<1, 256, 0, stream>>>(part, scale);
        quantize_w<<<(N * K / 4) / 256, 256, 0, stream>>>(W, wq, scale);
        cast_x<<<(M * K / 4) / 256, 256, 0, stream>>>(x, xh);
        qgemm<true><<<(M / 128) * (N / 128), 256, 0, stream>>>(xh, wq, out, scale, M, N, K);
    } else if (ws_size >= OFF_WQ + WQ_BYTES) {
        reduce_abs1<<<4096, 256, 0, stream>>>(W, part);
        reduce_abs2<<<1, 256, 0, stream>>>(part, scale);
        quantize_w<<<(N * K / 4) / 256, 256, 0, stream>>>(W, wq, scale);
        qgemm<false><<<(M / 128) * (N / 128), 256, 0, stream>>>(x, wq, out, scale, M, N, K);
    } else {
        reduce_abs1<<<4096, 256, 0, stream>>>(W, part);
        reduce_abs2<<<1, 256, 0, stream>>>(part, scale);
        naive_qgemm<<<dim3(N / 256, M), 256, 0, stream>>>(x, W, out, scale, M);
    }
}

// Round 18
// 309.381 us; speedup vs baseline: 15.2012x; 1.0068x over previous
//
#include <hip/hip_runtime.h>
#include <cstdint>
#include <cstddef>

#define IN_F 4096
#define OUT_F 4096

typedef __attribute__((ext_vector_type(8))) short bf16x8;
typedef __attribute__((ext_vector_type(4))) float f32x4;

__device__ __forceinline__ ushort f32_bf16_rne(float f) {
    uint32_t u = __builtin_bit_cast(uint32_t, f);
    uint32_t r = (u + 0x7FFFu + ((u >> 16) & 1u)) >> 16;
    return (ushort)r;
}

__device__ __forceinline__ void gload_lds16(const void* g, void* l) {
    __builtin_amdgcn_global_load_lds(
        (const __attribute__((address_space(1))) uint32_t*)g,
        (__attribute__((address_space(3))) uint32_t*)l,
        16, 0, 0);
}

// ---------- fused prologue (validated R14) ----------
__global__ void fused_reduce_cast(const float* __restrict__ W,
                                  float* __restrict__ part,
                                  const float* __restrict__ X,
                                  ushort* __restrict__ xh) {
    const int t = threadIdx.x;
    if (blockIdx.x < 4096) {
        __shared__ float sm[256];
        const int b = blockIdx.x;
        const float* p = W + (size_t)b * 4096;
        float s = 0.f;
#pragma unroll
        for (int j = 0; j < 16; ++j) s += fabsf(p[t + 256 * j]);
        sm[t] = s;
        __syncthreads();
        for (int w = 128; w > 0; w >>= 1) {
            if (t < w) sm[t] += sm[t + w];
            __syncthreads();
        }
        if (t == 0) part[b] = sm[0];
    } else {
        const int i = (blockIdx.x - 4096) * 256 + t;
        float4 v = ((const float4*)X)[i];
        ushort4 o;
        o.x = f32_bf16_rne(v.x); o.y = f32_bf16_rne(v.y);
        o.z = f32_bf16_rne(v.z); o.w = f32_bf16_rne(v.w);
        ((ushort4*)xh)[i] = o;
    }
}

__global__ void reduce_abs1(const float* __restrict__ W, float* __restrict__ part) {
    __shared__ float sm[256];
    const int b = blockIdx.x, t = threadIdx.x;
    const float* p = W + (size_t)b * 4096;
    float s = 0.f;
#pragma unroll
    for (int j = 0; j < 16; ++j) s += fabsf(p[t + 256 * j]);
    sm[t] = s;
    __syncthreads();
    for (int w = 128; w > 0; w >>= 1) {
        if (t < w) sm[t] += sm[t + w];
        __syncthreads();
    }
    if (t == 0) part[b] = sm[0];
}

__global__ void reduce_abs2(const float* __restrict__ part, float* __restrict__ scale) {
    __shared__ float sm[256];
    const int t = threadIdx.x;
    float s = 0.f;
#pragma unroll
    for (int j = 0; j < 16; ++j) s += part[t + 256 * j];
    sm[t] = s;
    __syncthreads();
    for (int w = 128; w > 0; w >>= 1) {
        if (t < w) sm[t] += sm[t + w];
        __syncthreads();
    }
    if (t == 0) {
        float m = sm[0] / 16777216.0f;
        *scale = fmaxf(m, 1e-8f);
    }
}

__global__ void quantize_w(const float* __restrict__ W, ushort* __restrict__ wq,
                           const float* __restrict__ scale_p) {
    const int i = blockIdx.x * 256 + threadIdx.x;
    const float s = *scale_p;
    float4 v = ((const float4*)W)[i];
    float q0 = fminf(fmaxf(rintf(v.x / s), -2.f), 2.f);
    float q1 = fminf(fmaxf(rintf(v.y / s), -2.f), 2.f);
    float q2 = fminf(fmaxf(rintf(v.z / s), -2.f), 2.f);
    float q3 = fminf(fmaxf(rintf(v.w / s), -2.f), 2.f);
    ushort4 o;
    o.x = f32_bf16_rne(q0); o.y = f32_bf16_rne(q1);
    o.z = f32_bf16_rne(q2); o.w = f32_bf16_rne(q3);
    ((ushort4*)wq)[i] = o;
}

__global__ void cast_x(const float* __restrict__ X, ushort* __restrict__ xh) {
    const int i = blockIdx.x * 256 + threadIdx.x;
    float4 v = ((const float4*)X)[i];
    ushort4 o;
    o.x = f32_bf16_rne(v.x); o.y = f32_bf16_rne(v.y);
    o.z = f32_bf16_rne(v.z); o.w = f32_bf16_rne(v.w);
    ((ushort4*)xh)[i] = o;
}

// ======= 256x256 GEMM: R12 8-phase + DEPTH-3 prefetch (R18) ================
// C = scale * (A @ B^T).  A:[M][K] bf16, B:[N][K] bf16 (both K-contiguous).
// 512 threads = 8 waves (2M x 4N); per-wave 128x64 output (acc[8][4], AGPR).
// LDS 128 KiB: 2 K-tile buffers x {A0,A1,B0,B1} 16-KiB halves, XOR-swizzled
// (byte ^= (r&7)<<4) via pre-swizzled global source + swizzled ds_read.
//
// R18 change (the one documented m201 parameter R12 deviated from): counted
// prefetch depth 3 half-tiles (vmcnt(6)) instead of 2 (vmcnt(4)), with the
// uniform stage stream that makes it race-free:
//  P1: read b01+a0 | stage B1(kt+1,nxt) | bar | lgkm0 | Q00 | bar
//  P2: read a1     | stage A0(kt+2,cur) | bar | lgkm0 | Q10 | bar
//  P3: read b23    | stage A1(kt+2,cur) | bar | lgkm0 | Q01 | bar
//  P4:             | stage B0(kt+2,cur) | vmcnt(6) | bar | lgkm0 | Q11 | bar
// WAR (>=1 lgkm-drained barrier after region's last read): A0 read P1 ->
// staged P2; A1 read P2 -> staged P3; B halves read P1+P3, drained P3 ->
// B0 staged P4, B1 staged next-P1.  RAW: vmcnt(6)@P4 leaves exactly the 3
// newest halves (= all of tile kt+2) in flight -> B1(kt+1) and older
// confirmed -> tile kt+1 fully landed before its P1 reads.
// Prologue: tile0 x4 + {A0,A1,B0}(tile1) = 7 halves; vmcnt(6) confirms
// tile0.  Tail: kt >= NT-2 -> vmcnt(0) (R6 lesson: skipped stages stop
// pushing the counter).
#define BK 64
#define BUF_BYTES 65536

__global__ __launch_bounds__(512, 2) void qgemm256(
        const ushort* __restrict__ Ab, const ushort* __restrict__ Bq,
        float* __restrict__ C, const float* __restrict__ scale_p,
        int M, int N, int K) {
    extern __shared__ __align__(16) char smem[];

    const int t = threadIdx.x;
    const int lane = t & 63;
    const int w = t >> 6;
    const int wr = w >> 2;
    const int wc = w & 3;
    const int bh = wc >> 1;

    // ---- 2D XCD-aware supertiling (validated R7: FETCH 541->197 MB) ----
    const int MT = M >> 8;
    const int NTiles = N >> 8;
    int mt, nt;
    if (MT == 32 && NTiles == 16 && gridDim.x == 512) {
        const int x = blockIdx.x & 7;
        const int j = blockIdx.x >> 3;
        const int jr = j & 31;
        const int r = j >> 5;
        mt = (x & 3) * 8 + (jr & 7);
        nt = r * 8 + (x >> 2) * 4 + (jr >> 3);
    } else {
        const int nwg = gridDim.x;
        int wg = blockIdx.x;
        if ((nwg & 7) == 0) wg = (wg & 7) * (nwg >> 3) + (wg >> 3);
        mt = wg % MT; nt = wg / MT;
    }
    const int m0 = mt << 8;
    const int n0 = nt << 8;

    const int NT = K / BK;

    int pre[2];
#pragma unroll
    for (int ks = 0; ks < 2; ++ks)
        pre[ks] = (lane & 15) * 128 +
                  (((ks * 64) + ((lane >> 4) * 16)) ^ ((lane & 7) << 4));

    const int rowA = t >> 3;
    const int colsw = ((t & 7) ^ ((t >> 3) & 7)) << 3;
    const ushort* gA0 = Ab + (size_t)(m0 + rowA) * K + colsw;
    const ushort* gA1 = Ab + (size_t)(m0 + 128 + rowA) * K + colsw;
    const ushort* gB0 = Bq + (size_t)(n0 + rowA) * K + colsw;
    const ushort* gB1 = Bq + (size_t)(n0 + 128 + rowA) * K + colsw;
    const size_t jrow = (size_t)64 * K;
    char* lb = smem + t * 16;

    auto stA0 = [&](uint32_t par) {
        gload_lds16(gA0,        lb + par);
        gload_lds16(gA0 + jrow, lb + par + 8192);
        gA0 += 64;
    };
    auto stA1 = [&](uint32_t par) {
        gload_lds16(gA1,        lb + par + 16384);
        gload_lds16(gA1 + jrow, lb + par + 24576);
        gA1 += 64;
    };
    auto stB0 = [&](uint32_t par) {
        gload_lds16(gB0,        lb + par + 32768);
        gload_lds16(gB0 + jrow, lb + par + 40960);
        gB0 += 64;
    };
    auto stB1 = [&](uint32_t par) {
        gload_lds16(gB1,        lb + par + 49152);
        gload_lds16(gB1 + jrow, lb + par + 57344);
        gB1 += 64;
    };

    const char* aBbase = smem + wr * 16384;
    const char* bBbase = smem + 32768 + bh * 16384 + (wc & 1) * 8192;

    f32x4 acc[8][4];
#pragma unroll
    for (int m = 0; m < 8; ++m)
#pragma unroll
        for (int n = 0; n < 4; ++n) acc[m][n] = (f32x4){0.f, 0.f, 0.f, 0.f};

    // ---- prologue: tile0 x4 + {A0,A1,B0}(tile1); vmcnt(6) confirms tile0 ----
    stB0(0); stB1(0); stA0(0); stA1(0);
    stA0(BUF_BYTES); stA1(BUF_BYTES); stB0(BUF_BYTES);
    asm volatile("s_waitcnt vmcnt(6)");
    __builtin_amdgcn_s_barrier();

    for (int kt = 0; kt < NT; ++kt) {
        const uint32_t cur = (uint32_t)(kt & 1) * BUF_BYTES;
        const uint32_t nxt = cur ^ BUF_BYTES;
        const char* aB = aBbase + cur;
        const char* bB = bBbase + cur;

        bf16x8 a0[4][2], a1[4][2], b01[2][2], b23[2][2];

        // -------- P1: read b01 + a0; stage B1(kt+1); Q00 --------
#pragma unroll
        for (int n = 0; n < 2; ++n)
#pragma unroll
            for (int ks = 0; ks < 2; ++ks)
                b01[n][ks] = *(const bf16x8*)(bB + n * 2048 + pre[ks]);
#pragma unroll
        for (int m = 0; m < 4; ++m)
#pragma unroll
            for (int ks = 0; ks < 2; ++ks)
                a0[m][ks] = *(const bf16x8*)(aB + m * 2048 + pre[ks]);
        if (kt + 1 < NT) stB1(nxt);
        __builtin_amdgcn_s_barrier();
        asm volatile("s_waitcnt lgkmcnt(0)");
        __builtin_amdgcn_s_setprio(1);
#pragma unroll
        for (int m = 0; m < 4; ++m)
#pragma unroll
            for (int n = 0; n < 2; ++n)
#pragma unroll
                for (int ks = 0; ks < 2; ++ks)
                    acc[m][n] = __builtin_amdgcn_mfma_f32_16x16x32_bf16(
                        a0[m][ks], b01[n][ks], acc[m][n], 0, 0, 0);
        __builtin_amdgcn_s_setprio(0);
        __builtin_amdgcn_s_barrier();

        // -------- P2: read a1; stage A0(kt+2); Q10 --------
#pragma unroll
        for (int m = 0; m < 4; ++m)
#pragma unroll
            for (int ks = 0; ks < 2; ++ks)
                a1[m][ks] = *(const bf16x8*)(aB + (m + 4) * 2048 + pre[ks]);
        if (kt + 2 < NT) stA0(cur);
        __builtin_amdgcn_s_barrier();
        asm volatile("s_waitcnt lgkmcnt(0)");
        __builtin_amdgcn_s_setprio(1);
#pragma unroll
        for (int m = 0; m < 4; ++m)
#pragma unroll
            for (int n = 0; n < 2; ++n)
#pragma unroll
                for (int ks = 0; ks < 2; ++ks)
                    acc[m + 4][n] = __builtin_amdgcn_mfma_f32_16x16x32_bf16(
                        a1[m][ks], b01[n][ks], acc[m + 4][n], 0, 0, 0);
        __builtin_amdgcn_s_setprio(0);
        __builtin_amdgcn_s_barrier();

        // -------- P3: read b23; stage A1(kt+2); Q01 --------
#pragma unroll
        for (int n = 0; n < 2; ++n)
#pragma unroll
            for (int ks = 0; ks < 2; ++ks)
                b23[n][ks] = *(const bf16x8*)(bB + (n + 2) * 2048 + pre[ks]);
        if (kt + 2 < NT) stA1(cur);
        __builtin_amdgcn_s_barrier();
        asm volatile("s_waitcnt lgkmcnt(0)");
        __builtin_amdgcn_s_setprio(1);
#pragma unroll
        for (int m = 0; m < 4; ++m)
#pragma unroll
            for (int n = 0; n < 2; ++n)
#pragma unroll
                for (int ks = 0; ks < 2; ++ks)
                    acc[m][n + 2] = __builtin_amdgcn_mfma_f32_16x16x32_bf16(
                        a0[m][ks], b23[n][ks], acc[m][n + 2], 0, 0, 0);
        __builtin_amdgcn_s_setprio(0);
        __builtin_amdgcn_s_barrier();

        // -------- P4: stage B0(kt+2); boundary vmcnt(6); Q11 --------
        if (kt + 2 < NT) stB0(cur);
        if (kt < NT - 2) {
            asm volatile("s_waitcnt vmcnt(6)");  // 3 newest halves (tile kt+2) in flight
        } else {
            asm volatile("s_waitcnt vmcnt(0)");  // tail drain (R6 lesson)
        }
        __builtin_amdgcn_s_barrier();
        asm volatile("s_waitcnt lgkmcnt(0)");
        __builtin_amdgcn_s_setprio(1);
#pragma unroll
        for (int m = 0; m < 4; ++m)
#pragma unroll
            for (int n = 0; n < 2; ++n)
#pragma unroll
                for (int ks = 0; ks < 2; ++ks)
                    acc[m + 4][n + 2] = __builtin_amdgcn_mfma_f32_16x16x32_bf16(
                        a1[m][ks], b23[n][ks], acc[m + 4][n + 2], 0, 0, 0);
        __builtin_amdgcn_s_setprio(0);
        __builtin_amdgcn_s_barrier();
    }

    const float s = *scale_p;
#pragma unroll
    for (int m = 0; m < 8; ++m)
#pragma unroll
        for (int n = 0; n < 4; ++n) {
            const int col = n0 + wc * 64 + n * 16 + (lane & 15);
            const int rbase = m0 + wr * 128 + m * 16 + ((lane >> 4) << 2);
#pragma unroll
            for (int j = 0; j < 4; ++j)
                C[(size_t)(rbase + j) * N + col] = s * acc[m][n][j];
        }
}

// ---------- 128^2 fallback (validated round 2) ----------
template <bool ABF16>
__global__ __launch_bounds__(256) void qgemm(const void* __restrict__ Aptr,
                                             const ushort* __restrict__ Bq,
                                             float* __restrict__ C,
                                             const float* __restrict__ scale_p,
                                             int M, int N, int K) {
    __shared__ __align__(16) ushort sA[128 * 64];
    __shared__ __align__(16) ushort sB[128 * 64];

    const int t = threadIdx.x;
    const int lane = t & 63;
    const int w = t >> 6;
    const int wr = w >> 1, wc = w & 1;

    const int nwg = gridDim.x;
    int wg = blockIdx.x;
    if ((nwg & 7) == 0) wg = (wg & 7) * (nwg >> 3) + (wg >> 3);
    const int MT = M >> 7;
    const int mt = wg % MT;
    const int nt = wg / MT;
    const int m0 = mt * 128, n0 = nt * 128;

    const ushort* Ab = (const ushort*)Aptr;
    const float* Af = (const float*)Aptr;

    f32x4 zero = {0.f, 0.f, 0.f, 0.f};
    f32x4 acc[4][4];
#pragma unroll
    for (int m = 0; m < 4; ++m)
#pragma unroll
        for (int n = 0; n < 4; ++n) acc[m][n] = zero;

    for (int k0 = 0; k0 < K; k0 += 64) {
#pragma unroll
        for (int i = 0; i < 4; ++i) {
            int e = i * 2048 + t * 8;
            int r = e >> 6, c8 = (e >> 3) & 7;
            int srcc = (c8 ^ (r & 7)) * 8;
            gload_lds16(Bq + (size_t)(n0 + r) * K + (k0 + srcc), &sB[e]);
        }
        if constexpr (ABF16) {
#pragma unroll
            for (int i = 0; i < 4; ++i) {
                int e = i * 2048 + t * 8;
                int r = e >> 6, c8 = (e >> 3) & 7;
                int srcc = (c8 ^ (r & 7)) * 8;
                gload_lds16(Ab + (size_t)(m0 + r) * K + (k0 + srcc), &sA[e]);
            }
        } else {
#pragma unroll
            for (int i = 0; i < 4; ++i) {
                int e = i * 2048 + t * 8;
                int r = e >> 6, c = e & 63;
                const float* src = Af + (size_t)(m0 + r) * K + (k0 + c);
                float4 v0 = *(const float4*)src;
                float4 v1 = *(const float4*)(src + 4);
                bf16x8 pk;
                pk[0] = (short)f32_bf16_rne(v0.x); pk[1] = (short)f32_bf16_rne(v0.y);
                pk[2] = (short)f32_bf16_rne(v0.z); pk[3] = (short)f32_bf16_rne(v0.w);
                pk[4] = (short)f32_bf16_rne(v1.x); pk[5] = (short)f32_bf16_rne(v1.y);
                pk[6] = (short)f32_bf16_rne(v1.z); pk[7] = (short)f32_bf16_rne(v1.w);
                int byte = (r * 128 + c * 2) ^ ((r & 7) << 4);
                *(bf16x8*)((char*)sA + byte) = pk;
            }
        }
        __syncthreads();

#pragma unroll
        for (int ks = 0; ks < 2; ++ks) {
            const int kk = ks * 32 + ((lane >> 4) << 3);
            bf16x8 afr[4], bfr[4];
#pragma unroll
            for (int m = 0; m < 4; ++m) {
                int r = wr * 64 + m * 16 + (lane & 15);
                int byte = (r * 128 + kk * 2) ^ ((r & 7) << 4);
                afr[m] = *(const bf16x8*)((const char*)sA + byte);
            }
#pragma unroll
            for (int n = 0; n < 4; ++n) {
                int r = wc * 64 + n * 16 + (lane & 15);
                int byte = (r * 128 + kk * 2) ^ ((r & 7) << 4);
                bfr[n] = *(const bf16x8*)((const char*)sB + byte);
            }
#pragma unroll
            for (int m = 0; m < 4; ++m)
#pragma unroll
                for (int n = 0; n < 4; ++n)
                    acc[m][n] = __builtin_amdgcn_mfma_f32_16x16x32_bf16(
                        afr[m], bfr[n], acc[m][n], 0, 0, 0);
        }
        __syncthreads();
    }

    const float s = *scale_p;
#pragma unroll
    for (int m = 0; m < 4; ++m)
#pragma unroll
        for (int n = 0; n < 4; ++n) {
            const int col = n0 + wc * 64 + n * 16 + (lane & 15);
            const int rbase = m0 + wr * 64 + m * 16 + ((lane >> 4) << 2);
#pragma unroll
            for (int j = 0; j < 4; ++j)
                C[(size_t)(rbase + j) * N + col] = s * acc[m][n][j];
        }
}

// ---------- last-resort naive path ----------
__global__ void naive_qgemm(const float* __restrict__ X, const float* __restrict__ W,
                            float* __restrict__ out, const float* __restrict__ scale_p,
                            int M) {
    const int col = blockIdx.x * 256 + threadIdx.x;
    const int row = blockIdx.y;
    const float s = *scale_p;
    const float inv = 1.0f / s;
    const float* xr = X + (size_t)row * IN_F;
    const float* wrow = W + (size_t)col * IN_F;
    float acc = 0.f;
    for (int k = 0; k < IN_F; ++k) {
        float q = fminf(fmaxf(rintf(wrow[k] * inv), -2.f), 2.f);
        acc += xr[k] * q;
    }
    out[(size_t)row * OUT_F + col] = acc * s;
}

extern "C" void kernel_launch(void* const* d_in, const int* in_sizes, int n_in,
                              void* d_out, int out_size, void* d_ws, size_t ws_size,
                              hipStream_t stream) {
    const float* x = (const float*)d_in[0];
    const float* W = (const float*)d_in[1];
    float* out = (float*)d_out;
    const int M = in_sizes[0] / IN_F;  // 8192
    const int K = IN_F, N = OUT_F;

    char* ws = (char*)d_ws;
    const size_t OFF_PART = 512;
    const size_t OFF_WQ = OFF_PART + 4096 * sizeof(float);
    const size_t WQ_BYTES = (size_t)N * K * sizeof(ushort);
    const size_t OFF_XH = OFF_WQ + WQ_BYTES;
    const size_t XH_BYTES = (size_t)M * K * sizeof(ushort);
    float* scale = (float*)(ws + 0);
    float* part = (float*)(ws + OFF_PART);
    ushort* wq = (ushort*)(ws + OFF_WQ);
    ushort* xh = (ushort*)(ws + OFF_XH);

    if (ws_size < OFF_WQ) return;

    if (ws_size >= OFF_XH + XH_BYTES && (M % 256) == 0 && (N % 256) == 0 &&
        (N * K) == 4096 * 4096) {
        const int castBlocks = (M * K / 4) / 256;
        fused_reduce_cast<<<4096 + castBlocks, 256, 0, stream>>>(W, part, x, xh);
        reduce_abs2<<<1, 256, 0, stream>>>(part, scale);
        quantize_w<<<(N * K / 4) / 256, 256, 0, stream>>>(W, wq, scale);
        (void)hipFuncSetAttribute((const void*)qgemm256,
                                  hipFuncAttributeMaxDynamicSharedMemorySize,
                                  131072);
        qgemm256<<<(M / 256) * (N / 256), 512, 131072, stream>>>(
            xh, wq, out, scale, M, N, K);
    } else if (ws_size >= OFF_XH + XH_BYTES) {
        reduce_abs1<<<4096, 256, 0, stream>>>(W, part);
        reduce_abs2<<<1, 256, 0, stream>>>(part, scale);
        quantize_w<<<(N * K / 4) / 256, 256, 0, stream>>>(W, wq, scale);
        cast_x<<<(M * K / 4) / 256, 256, 0, stream>>>(x, xh);
        qgemm<true><<<(M / 128) * (N / 128), 256, 0, stream>>>(xh, wq, out, scale, M, N, K);
    } else if (ws_size >= OFF_WQ + WQ_BYTES) {
        reduce_abs1<<<4096, 256, 0, stream>>>(W, part);
        reduce_abs2<<<1, 256, 0, stream>>>(part, scale);
        quantize_w<<<(N * K / 4) / 256, 256, 0, stream>>>(W, wq, scale);
        qgemm<false><<<(M / 128) * (N / 128), 256, 0, stream>>>(x, wq, out, scale, M, N, K);
    } else {
        reduce_abs1<<<4096, 256, 0, stream>>>(W, part);
        reduce_abs2<<<1, 256, 0, stream>>>(part, scale);
        naive_qgemm<<<dim3(N / 256, M), 256, 0, stream>>>(x, W, out, scale, M);
    }
}